// Round 3
// baseline (1221.088 us; speedup 1.0000x reference)
//
#include <hip/hip_runtime.h>

#define NN 50000
#define EE 600000
#define DD 128
#define DD2 256
#define LL 5
#define BN_EPS 1e-5f
#define GXF 512
#define NT1 782  // ceil(NN/64) row-tiles of 64

typedef __attribute__((ext_vector_type(8))) _Float16 half8;
typedef __attribute__((ext_vector_type(4))) float f32x4;

__device__ inline unsigned short f2h_bits(float f) {
    _Float16 h = (_Float16)f;  // RTNE
    return __builtin_bit_cast(unsigned short, h);
}
__device__ inline float h2f(unsigned short u) {
    return (float)__builtin_bit_cast(_Float16, u);
}
__device__ inline half8 bnrelu8(half8 v, half8 s, half8 t) {
    half8 r = v * s + t;
#pragma unroll
    for (int k = 0; k < 8; k++) r[k] = (r[k] > (_Float16)0) ? r[k] : (_Float16)0;
    return r;
}

// Software grid barrier (R2): hipLaunchCooperativeKernel is silently rejected under the
// harness's graph capture, so the fused kernel never ran (identical absmax across code
// changes). Grid=512 == 256CU x 2 blocks/CU (launch_bounds(256,2), 64KB LDS caps at 2/CU),
// so all blocks are co-resident and a spin barrier is deadlock-free.
__device__ inline void grid_barrier(int* bar) {
    __syncthreads();
    if (threadIdx.x == 0) {
        __threadfence();
        int t = __hip_atomic_fetch_add(&bar[0], 1, __ATOMIC_ACQ_REL, __HIP_MEMORY_SCOPE_AGENT);
        if (t == GXF - 1) {
            __hip_atomic_store(&bar[1], 1, __ATOMIC_RELEASE, __HIP_MEMORY_SCOPE_AGENT);
        } else {
            while (__hip_atomic_load(&bar[1], __ATOMIC_ACQUIRE, __HIP_MEMORY_SCOPE_AGENT) == 0) {
                __builtin_amdgcn_s_sleep(16);
            }
        }
        __threadfence();
    }
    __syncthreads();
}

// ---------------- CSR build ----------------

__global__ void hist_kernel(const int* __restrict__ dst, int* __restrict__ counts) {
    int e = blockIdx.x * blockDim.x + threadIdx.x;
    if (e < EE) atomicAdd(&counts[dst[e]], 1);
}

__global__ void scan1_kernel(const int* __restrict__ counts, int* __restrict__ row_ptr,
                             int* __restrict__ blksum) {
    __shared__ int tmp[256];
    int i = blockIdx.x * 256 + threadIdx.x;
    int v = (i < NN) ? counts[i] : 0;
    tmp[threadIdx.x] = v;
    __syncthreads();
    for (int off = 1; off < 256; off <<= 1) {
        int x = 0;
        if (threadIdx.x >= off) x = tmp[threadIdx.x - off];
        __syncthreads();
        if (threadIdx.x >= off) tmp[threadIdx.x] += x;
        __syncthreads();
    }
    if (i < NN) row_ptr[i] = tmp[threadIdx.x] - v;
    if (threadIdx.x == 255) blksum[blockIdx.x] = tmp[255];
}

__global__ void scan2_kernel(int* __restrict__ blksum, int nblocks) {
    __shared__ int tmp[256];
    int v = (threadIdx.x < nblocks) ? blksum[threadIdx.x] : 0;
    tmp[threadIdx.x] = v;
    __syncthreads();
    for (int off = 1; off < 256; off <<= 1) {
        int x = 0;
        if (threadIdx.x >= off) x = tmp[threadIdx.x - off];
        __syncthreads();
        if (threadIdx.x >= off) tmp[threadIdx.x] += x;
        __syncthreads();
    }
    blksum[threadIdx.x] = tmp[threadIdx.x] - v;
}

__global__ void scan3_kernel(int* __restrict__ row_ptr, const int* __restrict__ blksum) {
    int i = blockIdx.x * 256 + threadIdx.x;
    if (i < NN) row_ptr[i] += blksum[blockIdx.x];
    if (i == 0) row_ptr[NN] = EE;
}

// scatter + pack edge data: edata[p] = {src, cid | w_fp16<<16}
__global__ void scatter_kernel(const int* __restrict__ dst, const int* __restrict__ src,
                               const int* __restrict__ edge_attr, const float* __restrict__ ew,
                               const int* __restrict__ row_ptr, int* __restrict__ cursor,
                               uint2* __restrict__ edata) {
    int e = blockIdx.x * blockDim.x + threadIdx.x;
    if (e < EE) {
        int d = dst[e];
        int p = row_ptr[d] + atomicAdd(&cursor[d], 1);
        int cid = edge_attr[3 * e + 0] + 8 * edge_attr[3 * e + 1] + 64 * edge_attr[3 * e + 2];
        uint2 v;
        v.x = (unsigned)src[e];
        v.y = (unsigned)cid | ((unsigned)f2h_bits(ew[e]) << 16);
        edata[p] = v;
    }
}

// ---------------- table prep: W1t, W2t (fp16, [M][K]) + combined bond table (fp16) ------------

__global__ void prep_tables_kernel(const float* __restrict__ W1, const float* __restrict__ W2,
                                   const float* __restrict__ bond_emb,
                                   unsigned short* __restrict__ W1t,
                                   unsigned short* __restrict__ W2t,
                                   unsigned short* __restrict__ bsum) {
    const int NW = LL * DD * DD2;  // 163840
    int idx = blockIdx.x * 256 + threadIdx.x;
    if (idx < NW) {
        int l = idx / (DD * DD2);
        int rem = idx - l * DD * DD2;
        int k = rem / DD2, m = rem - k * DD2;  // W1: [L][128][256]
        W1t[(size_t)l * DD * DD2 + (size_t)m * DD + k] = f2h_bits(W1[idx]);
    } else if (idx < 2 * NW) {
        int j = idx - NW;
        int l = j / (DD * DD2);
        int rem = j - l * DD * DD2;
        int k = rem / DD, m = rem - k * DD;  // W2: [L][256][128]
        W2t[(size_t)l * DD * DD2 + (size_t)m * DD2 + k] = f2h_bits(W2[j]);
    } else if (idx < 2 * NW + LL * 512 * DD) {
        int j = idx - 2 * NW;
        int l = j >> 16;  // 512*128
        int rem = j & 65535;
        int cid = rem >> 7, d = rem & 127;
        int a0 = cid & 7, a1 = (cid >> 3) & 7, a2 = cid >> 6;
        const float* base = bond_emb + (size_t)l * 3 * 8 * DD;
        bsum[j] = f2h_bits(base[a0 * DD + d] + base[(8 + a1) * DD + d] + base[(16 + a2) * DD + d]);
    }
}

// ---------------- node init (fp16 h0) ----------------

__global__ void init_h_kernel(const int* __restrict__ x, const float* __restrict__ atom_emb,
                              unsigned short* __restrict__ h) {
    int n = blockIdx.x * 8 + (threadIdx.x >> 5);
    int lane = threadIdx.x & 31;
    float a0 = 0.f, a1 = 0.f, a2 = 0.f, a3 = 0.f;
#pragma unroll
    for (int f = 0; f < 9; f++) {
        int idx = x[n * 9 + f];
        const float4 v = *(const float4*)(atom_emb + ((size_t)(f * 64 + idx) * DD) + lane * 4);
        a0 += v.x; a1 += v.y; a2 += v.z; a3 += v.w;
    }
    ushort4 o;
    o.x = f2h_bits(a0); o.y = f2h_bits(a1); o.z = f2h_bits(a2); o.w = f2h_bits(a3);
    *(ushort4*)(h + (size_t)n * DD + lane * 4) = o;
}

// ---------------- edge aggregate → A fp16, optional fused BN2+relu on gathered rows ----------

template <bool FUSE>
__global__ void agg_kernel(const unsigned short* __restrict__ hsrc,
                           const float* __restrict__ stats, const float* __restrict__ g,
                           const float* __restrict__ bb, const int* __restrict__ row_ptr,
                           const uint2* __restrict__ edata,
                           const unsigned short* __restrict__ bsum_l,
                           const float* __restrict__ eps_ptr, unsigned short* __restrict__ Aout) {
    int n = blockIdx.x * 8 + (threadIdx.x >> 5);
    int lane = threadIdx.x & 31;
    int c0 = lane * 4;

    float bs[4] = {1.f, 1.f, 1.f, 1.f}, bt[4] = {0.f, 0.f, 0.f, 0.f};
    if (FUSE) {
        float4 sm = *(const float4*)(stats + c0);
        float4 sq = *(const float4*)(stats + DD + c0);
        float4 gg = *(const float4*)(g + c0);
        float4 bv = *(const float4*)(bb + c0);
        float mv[4] = {sm.x, sm.y, sm.z, sm.w};
        float qv[4] = {sq.x, sq.y, sq.z, sq.w};
        float gv[4] = {gg.x, gg.y, gg.z, gg.w};
        float bbv[4] = {bv.x, bv.y, bv.z, bv.w};
#pragma unroll
        for (int k = 0; k < 4; k++) {
            float mean = mv[k] * (1.f / NN);
            float var = qv[k] * (1.f / NN) - mean * mean;
            bs[k] = gv[k] * rsqrtf(var + BN_EPS);
            bt[k] = bbv[k] - mean * bs[k];
        }
    }

    auto accum = [&](uint2 ed, uint2 hz, uint2 bz, float* acc) {
        float w = h2f((unsigned short)(ed.y >> 16));
        unsigned int hw[2] = {hz.x, hz.y}, bw[2] = {bz.x, bz.y};
#pragma unroll
        for (int k = 0; k < 2; k++) {
            float hv0 = h2f((unsigned short)(hw[k] & 0xffff));
            float hv1 = h2f((unsigned short)(hw[k] >> 16));
            if (FUSE) {
                hv0 = fmaxf(hv0 * bs[2 * k] + bt[2 * k], 0.f);
                hv1 = fmaxf(hv1 * bs[2 * k + 1] + bt[2 * k + 1], 0.f);
            }
            float m0 = fmaxf(hv0 + h2f((unsigned short)(bw[k] & 0xffff)), 0.f);
            float m1 = fmaxf(hv1 + h2f((unsigned short)(bw[k] >> 16)), 0.f);
            acc[2 * k] += m0 * w;
            acc[2 * k + 1] += m1 * w;
        }
    };

    int beg = row_ptr[n], end = row_ptr[n + 1];
    float acc[4] = {0.f, 0.f, 0.f, 0.f};
    int i = beg;
    for (; i + 4 <= end; i += 4) {
        uint2 e0 = edata[i], e1 = edata[i + 1], e2 = edata[i + 2], e3 = edata[i + 3];
        uint2 h0 = *(const uint2*)(hsrc + (size_t)e0.x * DD + c0);
        uint2 b0 = *(const uint2*)(bsum_l + (size_t)(e0.y & 0xffff) * DD + c0);
        uint2 h1 = *(const uint2*)(hsrc + (size_t)e1.x * DD + c0);
        uint2 b1 = *(const uint2*)(bsum_l + (size_t)(e1.y & 0xffff) * DD + c0);
        uint2 h2 = *(const uint2*)(hsrc + (size_t)e2.x * DD + c0);
        uint2 b2 = *(const uint2*)(bsum_l + (size_t)(e2.y & 0xffff) * DD + c0);
        uint2 h3 = *(const uint2*)(hsrc + (size_t)e3.x * DD + c0);
        uint2 b3 = *(const uint2*)(bsum_l + (size_t)(e3.y & 0xffff) * DD + c0);
        accum(e0, h0, b0, acc);
        accum(e1, h1, b1, acc);
        accum(e2, h2, b2, acc);
        accum(e3, h3, b3, acc);
    }
    for (; i < end; i++) {
        uint2 e0 = edata[i];
        uint2 h0 = *(const uint2*)(hsrc + (size_t)e0.x * DD + c0);
        uint2 b0 = *(const uint2*)(bsum_l + (size_t)(e0.y & 0xffff) * DD + c0);
        accum(e0, h0, b0, acc);
    }

    float eps1 = 1.f + eps_ptr[0];
    uint2 hz = *(const uint2*)(hsrc + (size_t)n * DD + c0);
    unsigned int hw[2] = {hz.x, hz.y};
    float self[4];
#pragma unroll
    for (int k = 0; k < 2; k++) {
        float hv0 = h2f((unsigned short)(hw[k] & 0xffff));
        float hv1 = h2f((unsigned short)(hw[k] >> 16));
        if (FUSE) {
            hv0 = fmaxf(hv0 * bs[2 * k] + bt[2 * k], 0.f);
            hv1 = fmaxf(hv1 * bs[2 * k + 1] + bt[2 * k + 1], 0.f);
        }
        self[2 * k] = hv0;
        self[2 * k + 1] = hv1;
    }
    ushort4 o;
    o.x = f2h_bits(eps1 * self[0] + acc[0]);
    o.y = f2h_bits(eps1 * self[1] + acc[1]);
    o.z = f2h_bits(eps1 * self[2] + acc[2]);
    o.w = f2h_bits(eps1 * self[3] + acc[3]);
    *(ushort4*)(Aout + (size_t)n * DD + c0) = o;
}

// ---------------- fused GEMM1 + BN1 + relu + GEMM2, z1 resident in LDS ----------------
// Persistent kernel, 512 blocks = exactly 2/CU (launch_bounds(256,2), 64KB LDS).
// Phase 1: z1 tile (64 rows x 256 cols) = A @ W1 + b1 -> LDS fp16 (+ col stats atomics).
// Software grid barrier (see grid_barrier). Phase 2: BN1+relu on LDS fragments,
// z2 = z1bn @ W2 + b2 -> global (+ stats2).
// MFMA operands swapped (A-op = weight frags, B-op = row frags) so the 4 acc elements per
// fragment are 4 CONSECUTIVE COLUMNS -> packed ushort4 LDS writes / global stores.
// LDS swizzle: phys = (row*512 + colbyte) ^ ((row&7)<<4)  (row stride 512B == bank 0 unswizzled).
// R1 fix: phase-1 LDS store includes the wave's column offset (wave*128 bytes).
// R2: stats1 read with agent-scope atomic loads (plain loads could hit an XCD-L2 line cached
// during the PREVIOUS graph replay — no dispatch-boundary flush inside one kernel).

__global__ __launch_bounds__(256, 2) void fused_mlp_kernel(
    const unsigned short* __restrict__ A, const unsigned short* __restrict__ W1,
    const float* __restrict__ b1, const unsigned short* __restrict__ W2,
    const float* __restrict__ b2, const float* __restrict__ g1,
    const float* __restrict__ bb1, unsigned short* __restrict__ z2,
    float* __restrict__ stats1, float* __restrict__ stats2, int* bar) {
    __shared__ __align__(16) char ldsb[65536];  // 2 slots x [64 rows][256 cols] fp16
    const int lane = threadIdx.x & 63;
    const int wave = threadIdx.x >> 6;
    const int lr = lane & 15;
    const int q = lane >> 4;
    const int swz = (lr & 7) << 4;

    // ---- phase 1 ----
    {
        const int wcol = wave * 64;  // this wave's 64-col slice of z1
        half8 wf[4][4];
#pragma unroll
        for (int jm = 0; jm < 4; jm++) {
            const unsigned short* p = W1 + (size_t)(wcol + jm * 16 + lr) * DD + q * 8;
#pragma unroll
            for (int ks = 0; ks < 4; ks++)
                wf[jm][ks] = __builtin_bit_cast(half8, *(const int4*)(p + ks * 32));
        }
        float bi[4][4];
#pragma unroll
        for (int jm = 0; jm < 4; jm++)
#pragma unroll
            for (int r = 0; r < 4; r++) bi[jm][r] = b1[wcol + jm * 16 + q * 4 + r];

        float s1[16], sq1[16];
#pragma unroll
        for (int k = 0; k < 16; k++) { s1[k] = 0.f; sq1[k] = 0.f; }

        for (int s = 0; s < 2; s++) {
            int t = blockIdx.x + s * GXF;
            if (t >= NT1) break;
            int row0 = t * 64;
            // OOB rows (>=NN, <50048) read benign ws poison; results never stored/counted
            const unsigned short* ap0 = A + (size_t)(row0 + lr) * DD + q * 8;
            f32x4 acc[4][4];
#pragma unroll
            for (int jm = 0; jm < 4; jm++)
#pragma unroll
                for (int in = 0; in < 4; in++) acc[jm][in] = (f32x4){0.f, 0.f, 0.f, 0.f};
#pragma unroll
            for (int ks = 0; ks < 4; ks++) {
                half8 rf[4];
#pragma unroll
                for (int in = 0; in < 4; in++)
                    rf[in] = __builtin_bit_cast(
                        half8, *(const int4*)(ap0 + (size_t)(in * 16) * DD + ks * 32));
#pragma unroll
                for (int jm = 0; jm < 4; jm++)
#pragma unroll
                    for (int in = 0; in < 4; in++)
                        acc[jm][in] = __builtin_amdgcn_mfma_f32_16x16x32_f16(
                            wf[jm][ks], rf[in], acc[jm][in], 0, 0, 0);
            }
            char* slot = ldsb + s * 32768;
#pragma unroll
            for (int in = 0; in < 4; in++) {
                int row = in * 16 + lr;
                bool rv = (row0 + row) < NN;
                int rbase = row * 512 + wave * 128;  // wave's 64-col (128 B) offset
#pragma unroll
                for (int jm = 0; jm < 4; jm++) {
                    ushort4 o;
#pragma unroll
                    for (int r = 0; r < 4; r++) {
                        float v = acc[jm][in][r] + bi[jm][r];
                        ((unsigned short*)&o)[r] = f2h_bits(v);
                        if (rv) {
                            s1[jm * 4 + r] += v;
                            sq1[jm * 4 + r] += v * v;
                        }
                    }
                    *(ushort4*)(slot + ((rbase + jm * 32 + q * 8) ^ swz)) = o;
                }
            }
        }
#pragma unroll
        for (int k = 0; k < 16; k++) {
            float a = s1[k], b = sq1[k];
#pragma unroll
            for (int m = 1; m < 16; m <<= 1) {
                a += __shfl_xor(a, m);
                b += __shfl_xor(b, m);
            }
            if (lr == 0) {
                int c = wcol + (k >> 2) * 16 + q * 4 + (k & 3);
                unsafeAtomicAdd(&stats1[c], a);
                unsafeAtomicAdd(&stats1[DD2 + c], b);
            }
        }
    }

    grid_barrier(bar);

    // ---- phase 2 ----
    {
        const int cb2 = wave * 32;  // this wave's 32-col slice of z2
        half8 sa[8], ta[8];
#pragma unroll
        for (int ks = 0; ks < 8; ks++) {
#pragma unroll
            for (int e = 0; e < 8; e++) {
                int c = ks * 32 + q * 8 + e;
                float sv = __hip_atomic_load(&stats1[c], __ATOMIC_RELAXED,
                                             __HIP_MEMORY_SCOPE_AGENT);
                float qv = __hip_atomic_load(&stats1[DD2 + c], __ATOMIC_RELAXED,
                                             __HIP_MEMORY_SCOPE_AGENT);
                float mean = sv * (1.f / NN);
                float var = qv * (1.f / NN) - mean * mean;
                float sc = g1[c] * rsqrtf(var + BN_EPS);
                sa[ks][e] = (_Float16)sc;
                ta[ks][e] = (_Float16)(bb1[c] - mean * sc);
            }
        }
        half8 wf2[2][8];
#pragma unroll
        for (int jm = 0; jm < 2; jm++) {
            const unsigned short* p = W2 + (size_t)(cb2 + jm * 16 + lr) * DD2 + q * 8;
#pragma unroll
            for (int ks = 0; ks < 8; ks++)
                wf2[jm][ks] = __builtin_bit_cast(half8, *(const int4*)(p + ks * 32));
        }
        float bi2[2][4];
#pragma unroll
        for (int jm = 0; jm < 2; jm++)
#pragma unroll
            for (int r = 0; r < 4; r++) bi2[jm][r] = b2[cb2 + jm * 16 + q * 4 + r];

        float s2[8], sq2[8];
#pragma unroll
        for (int k = 0; k < 8; k++) { s2[k] = 0.f; sq2[k] = 0.f; }

        for (int s = 0; s < 2; s++) {
            int t = blockIdx.x + s * GXF;
            if (t >= NT1) break;
            int row0 = t * 64;
            char* slot = ldsb + s * 32768;
            f32x4 acc[2][4];
#pragma unroll
            for (int jm = 0; jm < 2; jm++)
#pragma unroll
                for (int in = 0; in < 4; in++) acc[jm][in] = (f32x4){0.f, 0.f, 0.f, 0.f};
#pragma unroll
            for (int ks = 0; ks < 8; ks++) {
                half8 rf[4];
#pragma unroll
                for (int in = 0; in < 4; in++) {
                    int row = in * 16 + lr;
                    half8 z = *(const half8*)(slot + ((row * 512 + ks * 64 + q * 16) ^ swz));
                    rf[in] = bnrelu8(z, sa[ks], ta[ks]);
                }
#pragma unroll
                for (int jm = 0; jm < 2; jm++)
#pragma unroll
                    for (int in = 0; in < 4; in++)
                        acc[jm][in] = __builtin_amdgcn_mfma_f32_16x16x32_f16(
                            wf2[jm][ks], rf[in], acc[jm][in], 0, 0, 0);
            }
#pragma unroll
            for (int in = 0; in < 4; in++) {
                int row = row0 + in * 16 + lr;
                if (row < NN) {
#pragma unroll
                    for (int jm = 0; jm < 2; jm++) {
                        ushort4 o;
#pragma unroll
                        for (int r = 0; r < 4; r++) {
                            float v = acc[jm][in][r] + bi2[jm][r];
                            ((unsigned short*)&o)[r] = f2h_bits(v);
                            s2[jm * 4 + r] += v;
                            sq2[jm * 4 + r] += v * v;
                        }
                        *(ushort4*)(z2 + (size_t)row * DD + cb2 + jm * 16 + q * 4) = o;
                    }
                }
            }
        }
#pragma unroll
        for (int k = 0; k < 8; k++) {
            float a = s2[k], b = sq2[k];
#pragma unroll
            for (int m = 1; m < 16; m <<= 1) {
                a += __shfl_xor(a, m);
                b += __shfl_xor(b, m);
            }
            if (lr == 0) {
                int c = cb2 + (k >> 2) * 16 + q * 4 + (k & 3);
                unsafeAtomicAdd(&stats2[c], a);
                unsafeAtomicAdd(&stats2[DD + c], b);
            }
        }
    }
}

// ---------------- BN apply 2, last layer only: z2 fp16 -> d_out fp32 (no relu) ---------------

__global__ void bnapply2_last_kernel(const unsigned short* __restrict__ z,
                                     const float* __restrict__ stats, const float* __restrict__ g,
                                     const float* __restrict__ bb, float* __restrict__ fout) {
    __shared__ float s_sh[DD], t_sh[DD];
    if (threadIdx.x < DD) {
        int c = threadIdx.x;
        float mean = stats[c] * (1.f / NN);
        float var = stats[DD + c] * (1.f / NN) - mean * mean;
        float sc = g[c] * rsqrtf(var + BN_EPS);
        s_sh[c] = sc;
        t_sh[c] = bb[c] - mean * sc;
    }
    __syncthreads();
    int i = (blockIdx.x * 256 + threadIdx.x) * 4;
    int c = i & 127;
    uint2 in = *(const uint2*)(z + i);
    float4 out;
    out.x = h2f((unsigned short)(in.x & 0xffff)) * s_sh[c] + t_sh[c];
    out.y = h2f((unsigned short)(in.x >> 16)) * s_sh[c + 1] + t_sh[c + 1];
    out.z = h2f((unsigned short)(in.y & 0xffff)) * s_sh[c + 2] + t_sh[c + 2];
    out.w = h2f((unsigned short)(in.y >> 16)) * s_sh[c + 3] + t_sh[c + 3];
    *(float4*)(fout + i) = out;
}

// ---------------- launch ----------------

extern "C" void kernel_launch(void* const* d_in, const int* in_sizes, int n_in,
                              void* d_out, int out_size, void* d_ws, size_t ws_size,
                              hipStream_t stream) {
    const int* x = (const int*)d_in[0];
    const int* edge_index = (const int*)d_in[1];
    const int* edge_attr = (const int*)d_in[2];
    const float* edge_weight = (const float*)d_in[3];
    const float* atom_emb = (const float*)d_in[4];
    const float* bond_emb = (const float*)d_in[5];
    const float* W1 = (const float*)d_in[6];
    const float* b1 = (const float*)d_in[7];
    const float* bn1_g = (const float*)d_in[8];
    const float* bn1_b = (const float*)d_in[9];
    const float* W2 = (const float*)d_in[10];
    const float* b2 = (const float*)d_in[11];
    const float* eps_p = (const float*)d_in[12];
    const float* bn_g = (const float*)d_in[13];
    const float* bn_b = (const float*)d_in[14];
    const int* srcv = edge_index;
    const int* dstv = edge_index + EE;

    char* p = (char*)d_ws;
    auto alloc = [&](size_t bytes) {
        void* r = (void*)p;
        p += (bytes + 255) & ~(size_t)255;
        return r;
    };
    // A1h padded to NT1*64 rows so fused kernel's tail-tile reads stay in-buffer
    unsigned short* h = (unsigned short*)alloc((size_t)NN * DD * 2);
    unsigned short* A1h = (unsigned short*)alloc((size_t)(NT1 * 64) * DD * 2);
    unsigned short* z2 = (unsigned short*)alloc((size_t)NN * DD * 2);
    uint2* edata = (uint2*)alloc((size_t)EE * 8);
    int* counts = (int*)alloc((size_t)NN * 4);
    int* row_ptr = (int*)alloc((size_t)(NN + 1) * 4);
    int* blksum = (int*)alloc(256 * 4);
    unsigned short* W1t = (unsigned short*)alloc((size_t)LL * DD * DD2 * 2);
    unsigned short* W2t = (unsigned short*)alloc((size_t)LL * DD * DD2 * 2);
    unsigned short* bsum = (unsigned short*)alloc((size_t)LL * 512 * DD * 2);
    // stats + barrier slots zeroed together, in-graph, so every replay resets them
    float* statsAll = (float*)alloc((size_t)(LL * 512 + LL * 256 + LL * 2) * 4);
    float* stats1Base = statsAll;
    float* stats2Base = statsAll + LL * 512;
    int* barriers = (int*)(statsAll + LL * 512 + LL * 256);

    // --- one-time prep ---
    hipMemsetAsync(counts, 0, (size_t)NN * 4, stream);
    hipMemsetAsync(statsAll, 0, (size_t)(LL * 512 + LL * 256 + LL * 2) * 4, stream);
    hist_kernel<<<(EE + 255) / 256, 256, 0, stream>>>(dstv, counts);
    int nblk = (NN + 255) / 256;
    scan1_kernel<<<nblk, 256, 0, stream>>>(counts, row_ptr, blksum);
    scan2_kernel<<<1, 256, 0, stream>>>(blksum, nblk);
    scan3_kernel<<<nblk, 256, 0, stream>>>(row_ptr, blksum);
    hipMemsetAsync(counts, 0, (size_t)NN * 4, stream);
    scatter_kernel<<<(EE + 255) / 256, 256, 0, stream>>>(dstv, srcv, edge_attr, edge_weight,
                                                         row_ptr, counts, edata);
    prep_tables_kernel<<<(2 * LL * DD * DD2 + LL * 512 * DD + 255) / 256, 256, 0, stream>>>(
        W1, W2, bond_emb, W1t, W2t, bsum);
    init_h_kernel<<<NN / 8, 256, 0, stream>>>(x, atom_emb, h);

    for (int l = 0; l < LL; l++) {
        float* stats1 = stats1Base + l * 512;
        float* stats2 = stats2Base + l * 256;
        const unsigned short* bsum_l = bsum + (size_t)l * 512 * DD;

        if (l == 0) {
            agg_kernel<false><<<NN / 8, 256, 0, stream>>>(h, nullptr, nullptr, nullptr, row_ptr,
                                                          edata, bsum_l, eps_p + l, A1h);
        } else {
            agg_kernel<true><<<NN / 8, 256, 0, stream>>>(
                z2, stats2Base + (l - 1) * 256, bn_g + (l - 1) * DD, bn_b + (l - 1) * DD, row_ptr,
                edata, bsum_l, eps_p + l, A1h);
        }

        fused_mlp_kernel<<<GXF, 256, 0, stream>>>(
            A1h, W1t + (size_t)l * DD * DD2, b1 + l * DD2, W2t + (size_t)l * DD * DD2,
            b2 + l * DD, bn1_g + l * DD2, bn1_b + l * DD2, z2, stats1, stats2, barriers + l * 2);
    }

    bnapply2_last_kernel<<<NN * DD / 1024, 256, 0, stream>>>(
        z2, stats2Base + (LL - 1) * 256, bn_g + (LL - 1) * DD, bn_b + (LL - 1) * DD,
        (float*)d_out);
}

// Round 4
// 1180.153 us; speedup vs baseline: 1.0347x; 1.0347x over previous
//
#include <hip/hip_runtime.h>

#define NN 50000
#define EE 600000
#define DD 128
#define DD2 256
#define LL 5
#define BN_EPS 1e-5f
#define GXF 512
#define NT1 782  // ceil(NN/64) row-tiles of 64

typedef __attribute__((ext_vector_type(8))) _Float16 half8;
typedef __attribute__((ext_vector_type(4))) float f32x4;

__device__ inline unsigned short f2h_bits(float f) {
    _Float16 h = (_Float16)f;  // RTNE
    return __builtin_bit_cast(unsigned short, h);
}
__device__ inline float h2f(unsigned short u) {
    return (float)__builtin_bit_cast(_Float16, u);
}
__device__ inline half8 bnrelu8(half8 v, half8 s, half8 t) {
    half8 r = v * s + t;
#pragma unroll
    for (int k = 0; k < 8; k++) r[k] = (r[k] > (_Float16)0) ? r[k] : (_Float16)0;
    return r;
}

// Software grid barrier (R2): hipLaunchCooperativeKernel is silently rejected under the
// harness's graph capture. Grid=512 == 256CU x 2 blocks/CU (launch_bounds(256,2), 66KB LDS
// caps at 2/CU), so all blocks are co-resident and a spin barrier is deadlock-free.
__device__ inline void grid_barrier(int* bar) {
    __syncthreads();
    if (threadIdx.x == 0) {
        __threadfence();
        int t = __hip_atomic_fetch_add(&bar[0], 1, __ATOMIC_ACQ_REL, __HIP_MEMORY_SCOPE_AGENT);
        if (t == GXF - 1) {
            __hip_atomic_store(&bar[1], 1, __ATOMIC_RELEASE, __HIP_MEMORY_SCOPE_AGENT);
        } else {
            while (__hip_atomic_load(&bar[1], __ATOMIC_ACQUIRE, __HIP_MEMORY_SCOPE_AGENT) == 0) {
                __builtin_amdgcn_s_sleep(16);
            }
        }
        __threadfence();
    }
    __syncthreads();
}

// ---------------- CSR build ----------------

__global__ void hist_kernel(const int* __restrict__ dst, int* __restrict__ counts) {
    int e = blockIdx.x * blockDim.x + threadIdx.x;
    if (e < EE) atomicAdd(&counts[dst[e]], 1);
}

__global__ void scan1_kernel(const int* __restrict__ counts, int* __restrict__ row_ptr,
                             int* __restrict__ blksum) {
    __shared__ int tmp[256];
    int i = blockIdx.x * 256 + threadIdx.x;
    int v = (i < NN) ? counts[i] : 0;
    tmp[threadIdx.x] = v;
    __syncthreads();
    for (int off = 1; off < 256; off <<= 1) {
        int x = 0;
        if (threadIdx.x >= off) x = tmp[threadIdx.x - off];
        __syncthreads();
        if (threadIdx.x >= off) tmp[threadIdx.x] += x;
        __syncthreads();
    }
    if (i < NN) row_ptr[i] = tmp[threadIdx.x] - v;
    if (threadIdx.x == 255) blksum[blockIdx.x] = tmp[255];
}

__global__ void scan2_kernel(int* __restrict__ blksum, int nblocks) {
    __shared__ int tmp[256];
    int v = (threadIdx.x < nblocks) ? blksum[threadIdx.x] : 0;
    tmp[threadIdx.x] = v;
    __syncthreads();
    for (int off = 1; off < 256; off <<= 1) {
        int x = 0;
        if (threadIdx.x >= off) x = tmp[threadIdx.x - off];
        __syncthreads();
        if (threadIdx.x >= off) tmp[threadIdx.x] += x;
        __syncthreads();
    }
    blksum[threadIdx.x] = tmp[threadIdx.x] - v;
}

__global__ void scan3_kernel(int* __restrict__ row_ptr, const int* __restrict__ blksum) {
    int i = blockIdx.x * 256 + threadIdx.x;
    if (i < NN) row_ptr[i] += blksum[blockIdx.x];
    if (i == 0) row_ptr[NN] = EE;
}

// scatter + pack edge data: edata[p] = {src, cid | w_fp16<<16}
__global__ void scatter_kernel(const int* __restrict__ dst, const int* __restrict__ src,
                               const int* __restrict__ edge_attr, const float* __restrict__ ew,
                               const int* __restrict__ row_ptr, int* __restrict__ cursor,
                               uint2* __restrict__ edata) {
    int e = blockIdx.x * blockDim.x + threadIdx.x;
    if (e < EE) {
        int d = dst[e];
        int p = row_ptr[d] + atomicAdd(&cursor[d], 1);
        int cid = edge_attr[3 * e + 0] + 8 * edge_attr[3 * e + 1] + 64 * edge_attr[3 * e + 2];
        uint2 v;
        v.x = (unsigned)src[e];
        v.y = (unsigned)cid | ((unsigned)f2h_bits(ew[e]) << 16);
        edata[p] = v;
    }
}

// ---------------- table prep: W1t, W2t (fp16, [M][K]) + combined bond table (fp16) ------------

__global__ void prep_tables_kernel(const float* __restrict__ W1, const float* __restrict__ W2,
                                   const float* __restrict__ bond_emb,
                                   unsigned short* __restrict__ W1t,
                                   unsigned short* __restrict__ W2t,
                                   unsigned short* __restrict__ bsum) {
    const int NW = LL * DD * DD2;  // 163840
    int idx = blockIdx.x * 256 + threadIdx.x;
    if (idx < NW) {
        int l = idx / (DD * DD2);
        int rem = idx - l * DD * DD2;
        int k = rem / DD2, m = rem - k * DD2;  // W1: [L][128][256]
        W1t[(size_t)l * DD * DD2 + (size_t)m * DD + k] = f2h_bits(W1[idx]);
    } else if (idx < 2 * NW) {
        int j = idx - NW;
        int l = j / (DD * DD2);
        int rem = j - l * DD * DD2;
        int k = rem / DD, m = rem - k * DD;  // W2: [L][256][128]
        W2t[(size_t)l * DD * DD2 + (size_t)m * DD2 + k] = f2h_bits(W2[j]);
    } else if (idx < 2 * NW + LL * 512 * DD) {
        int j = idx - 2 * NW;
        int l = j >> 16;  // 512*128
        int rem = j & 65535;
        int cid = rem >> 7, d = rem & 127;
        int a0 = cid & 7, a1 = (cid >> 3) & 7, a2 = cid >> 6;
        const float* base = bond_emb + (size_t)l * 3 * 8 * DD;
        bsum[j] = f2h_bits(base[a0 * DD + d] + base[(8 + a1) * DD + d] + base[(16 + a2) * DD + d]);
    }
}

// ---------------- node init (fp16 h0) ----------------

__global__ void init_h_kernel(const int* __restrict__ x, const float* __restrict__ atom_emb,
                              unsigned short* __restrict__ h) {
    int n = blockIdx.x * 8 + (threadIdx.x >> 5);
    int lane = threadIdx.x & 31;
    float a0 = 0.f, a1 = 0.f, a2 = 0.f, a3 = 0.f;
#pragma unroll
    for (int f = 0; f < 9; f++) {
        int idx = x[n * 9 + f];
        const float4 v = *(const float4*)(atom_emb + ((size_t)(f * 64 + idx) * DD) + lane * 4);
        a0 += v.x; a1 += v.y; a2 += v.z; a3 += v.w;
    }
    ushort4 o;
    o.x = f2h_bits(a0); o.y = f2h_bits(a1); o.z = f2h_bits(a2); o.w = f2h_bits(a3);
    *(ushort4*)(h + (size_t)n * DD + lane * 4) = o;
}

// ---------------- edge aggregate → A fp16, optional fused BN2+relu on gathered rows ----------

template <bool FUSE>
__global__ void agg_kernel(const unsigned short* __restrict__ hsrc,
                           const float* __restrict__ stats, const float* __restrict__ g,
                           const float* __restrict__ bb, const int* __restrict__ row_ptr,
                           const uint2* __restrict__ edata,
                           const unsigned short* __restrict__ bsum_l,
                           const float* __restrict__ eps_ptr, unsigned short* __restrict__ Aout) {
    int n = blockIdx.x * 8 + (threadIdx.x >> 5);
    int lane = threadIdx.x & 31;
    int c0 = lane * 4;

    float bs[4] = {1.f, 1.f, 1.f, 1.f}, bt[4] = {0.f, 0.f, 0.f, 0.f};
    if (FUSE) {
        float4 sm = *(const float4*)(stats + c0);
        float4 sq = *(const float4*)(stats + DD + c0);
        float4 gg = *(const float4*)(g + c0);
        float4 bv = *(const float4*)(bb + c0);
        float mv[4] = {sm.x, sm.y, sm.z, sm.w};
        float qv[4] = {sq.x, sq.y, sq.z, sq.w};
        float gv[4] = {gg.x, gg.y, gg.z, gg.w};
        float bbv[4] = {bv.x, bv.y, bv.z, bv.w};
#pragma unroll
        for (int k = 0; k < 4; k++) {
            float mean = mv[k] * (1.f / NN);
            float var = qv[k] * (1.f / NN) - mean * mean;
            bs[k] = gv[k] * rsqrtf(var + BN_EPS);
            bt[k] = bbv[k] - mean * bs[k];
        }
    }

    auto accum = [&](uint2 ed, uint2 hz, uint2 bz, float* acc) {
        float w = h2f((unsigned short)(ed.y >> 16));
        unsigned int hw[2] = {hz.x, hz.y}, bw[2] = {bz.x, bz.y};
#pragma unroll
        for (int k = 0; k < 2; k++) {
            float hv0 = h2f((unsigned short)(hw[k] & 0xffff));
            float hv1 = h2f((unsigned short)(hw[k] >> 16));
            if (FUSE) {
                hv0 = fmaxf(hv0 * bs[2 * k] + bt[2 * k], 0.f);
                hv1 = fmaxf(hv1 * bs[2 * k + 1] + bt[2 * k + 1], 0.f);
            }
            float m0 = fmaxf(hv0 + h2f((unsigned short)(bw[k] & 0xffff)), 0.f);
            float m1 = fmaxf(hv1 + h2f((unsigned short)(bw[k] >> 16)), 0.f);
            acc[2 * k] += m0 * w;
            acc[2 * k + 1] += m1 * w;
        }
    };

    int beg = row_ptr[n], end = row_ptr[n + 1];
    float acc[4] = {0.f, 0.f, 0.f, 0.f};
    int i = beg;
    for (; i + 4 <= end; i += 4) {
        uint2 e0 = edata[i], e1 = edata[i + 1], e2 = edata[i + 2], e3 = edata[i + 3];
        uint2 h0 = *(const uint2*)(hsrc + (size_t)e0.x * DD + c0);
        uint2 b0 = *(const uint2*)(bsum_l + (size_t)(e0.y & 0xffff) * DD + c0);
        uint2 h1 = *(const uint2*)(hsrc + (size_t)e1.x * DD + c0);
        uint2 b1 = *(const uint2*)(bsum_l + (size_t)(e1.y & 0xffff) * DD + c0);
        uint2 h2 = *(const uint2*)(hsrc + (size_t)e2.x * DD + c0);
        uint2 b2 = *(const uint2*)(bsum_l + (size_t)(e2.y & 0xffff) * DD + c0);
        uint2 h3 = *(const uint2*)(hsrc + (size_t)e3.x * DD + c0);
        uint2 b3 = *(const uint2*)(bsum_l + (size_t)(e3.y & 0xffff) * DD + c0);
        accum(e0, h0, b0, acc);
        accum(e1, h1, b1, acc);
        accum(e2, h2, b2, acc);
        accum(e3, h3, b3, acc);
    }
    for (; i < end; i++) {
        uint2 e0 = edata[i];
        uint2 h0 = *(const uint2*)(hsrc + (size_t)e0.x * DD + c0);
        uint2 b0 = *(const uint2*)(bsum_l + (size_t)(e0.y & 0xffff) * DD + c0);
        accum(e0, h0, b0, acc);
    }

    float eps1 = 1.f + eps_ptr[0];
    uint2 hz = *(const uint2*)(hsrc + (size_t)n * DD + c0);
    unsigned int hw[2] = {hz.x, hz.y};
    float self[4];
#pragma unroll
    for (int k = 0; k < 2; k++) {
        float hv0 = h2f((unsigned short)(hw[k] & 0xffff));
        float hv1 = h2f((unsigned short)(hw[k] >> 16));
        if (FUSE) {
            hv0 = fmaxf(hv0 * bs[2 * k] + bt[2 * k], 0.f);
            hv1 = fmaxf(hv1 * bs[2 * k + 1] + bt[2 * k + 1], 0.f);
        }
        self[2 * k] = hv0;
        self[2 * k + 1] = hv1;
    }
    ushort4 o;
    o.x = f2h_bits(eps1 * self[0] + acc[0]);
    o.y = f2h_bits(eps1 * self[1] + acc[1]);
    o.z = f2h_bits(eps1 * self[2] + acc[2]);
    o.w = f2h_bits(eps1 * self[3] + acc[3]);
    *(ushort4*)(Aout + (size_t)n * DD + c0) = o;
}

// ---------------- fused GEMM1 + BN1 + relu + GEMM2, z1 resident in LDS ----------------
// Persistent kernel, 512 blocks = exactly 2/CU (launch_bounds(256,2), 66KB LDS).
// Phase 1: z1 tile (64 rows x 256 cols) = A @ W1 + b1 -> LDS fp16 (+ col stats atomics).
// Software grid barrier. Phase 2: BN1 scale/shift broadcast via LDS, relu on LDS fragments,
// z2 = z1bn @ W2 + b2 -> global (+ stats2).
// MFMA operands swapped (A-op = weight frags, B-op = row frags) so the 4 acc elements per
// fragment are 4 CONSECUTIVE COLUMNS -> packed ushort4 LDS writes / global stores.
// LDS swizzle: phys = (row*512 + colbyte) ^ ((lr&7)<<4).
// R3 fix: stats1 read ONCE per block into st_sh (512 agent-scope atomic loads/block), not
// per-thread-per-element (was 32768/block = 16.7M device-wide atomic loads hammering 16
// cache lines -> 178us idle-stall dispatches, MfmaUtil 1.4%).

__global__ __launch_bounds__(256, 2) void fused_mlp_kernel(
    const unsigned short* __restrict__ A, const unsigned short* __restrict__ W1,
    const float* __restrict__ b1, const unsigned short* __restrict__ W2,
    const float* __restrict__ b2, const float* __restrict__ g1,
    const float* __restrict__ bb1, unsigned short* __restrict__ z2,
    float* __restrict__ stats1, float* __restrict__ stats2, int* bar) {
    __shared__ __align__(16) char ldsb[65536];  // 2 slots x [64 rows][256 cols] fp16
    __shared__ __align__(16) float st_sh[2 * DD2];  // BN1 scale/shift broadcast
    const int lane = threadIdx.x & 63;
    const int wave = threadIdx.x >> 6;
    const int lr = lane & 15;
    const int q = lane >> 4;
    const int swz = (lr & 7) << 4;

    // ---- phase 1 ----
    {
        const int wcol = wave * 64;  // this wave's 64-col slice of z1
        half8 wf[4][4];
#pragma unroll
        for (int jm = 0; jm < 4; jm++) {
            const unsigned short* p = W1 + (size_t)(wcol + jm * 16 + lr) * DD + q * 8;
#pragma unroll
            for (int ks = 0; ks < 4; ks++)
                wf[jm][ks] = __builtin_bit_cast(half8, *(const int4*)(p + ks * 32));
        }
        float bi[4][4];
#pragma unroll
        for (int jm = 0; jm < 4; jm++)
#pragma unroll
            for (int r = 0; r < 4; r++) bi[jm][r] = b1[wcol + jm * 16 + q * 4 + r];

        float s1[16], sq1[16];
#pragma unroll
        for (int k = 0; k < 16; k++) { s1[k] = 0.f; sq1[k] = 0.f; }

        for (int s = 0; s < 2; s++) {
            int t = blockIdx.x + s * GXF;
            if (t >= NT1) break;
            int row0 = t * 64;
            // OOB rows (>=NN, <50048) read benign ws poison; results never stored/counted
            const unsigned short* ap0 = A + (size_t)(row0 + lr) * DD + q * 8;
            f32x4 acc[4][4];
#pragma unroll
            for (int jm = 0; jm < 4; jm++)
#pragma unroll
                for (int in = 0; in < 4; in++) acc[jm][in] = (f32x4){0.f, 0.f, 0.f, 0.f};
#pragma unroll
            for (int ks = 0; ks < 4; ks++) {
                half8 rf[4];
#pragma unroll
                for (int in = 0; in < 4; in++)
                    rf[in] = __builtin_bit_cast(
                        half8, *(const int4*)(ap0 + (size_t)(in * 16) * DD + ks * 32));
#pragma unroll
                for (int jm = 0; jm < 4; jm++)
#pragma unroll
                    for (int in = 0; in < 4; in++)
                        acc[jm][in] = __builtin_amdgcn_mfma_f32_16x16x32_f16(
                            wf[jm][ks], rf[in], acc[jm][in], 0, 0, 0);
            }
            char* slot = ldsb + s * 32768;
#pragma unroll
            for (int in = 0; in < 4; in++) {
                int row = in * 16 + lr;
                bool rv = (row0 + row) < NN;
                int rbase = row * 512 + wave * 128;  // wave's 64-col (128 B) offset
#pragma unroll
                for (int jm = 0; jm < 4; jm++) {
                    ushort4 o;
#pragma unroll
                    for (int r = 0; r < 4; r++) {
                        float v = acc[jm][in][r] + bi[jm][r];
                        ((unsigned short*)&o)[r] = f2h_bits(v);
                        if (rv) {
                            s1[jm * 4 + r] += v;
                            sq1[jm * 4 + r] += v * v;
                        }
                    }
                    *(ushort4*)(slot + ((rbase + jm * 32 + q * 8) ^ swz)) = o;
                }
            }
        }
#pragma unroll
        for (int k = 0; k < 16; k++) {
            float a = s1[k], b = sq1[k];
#pragma unroll
            for (int m = 1; m < 16; m <<= 1) {
                a += __shfl_xor(a, m);
                b += __shfl_xor(b, m);
            }
            if (lr == 0) {
                int c = wcol + (k >> 2) * 16 + q * 4 + (k & 3);
                unsafeAtomicAdd(&stats1[c], a);
                unsafeAtomicAdd(&stats1[DD2 + c], b);
            }
        }
    }

    grid_barrier(bar);

    // ---- phase 2 ----
    {
        // BN1 scale/shift: one coalesced pass per block into LDS (R3 fix)
        for (int c = threadIdx.x; c < DD2; c += 256) {
            float sv = __hip_atomic_load(&stats1[c], __ATOMIC_RELAXED, __HIP_MEMORY_SCOPE_AGENT);
            float qv =
                __hip_atomic_load(&stats1[DD2 + c], __ATOMIC_RELAXED, __HIP_MEMORY_SCOPE_AGENT);
            float mean = sv * (1.f / NN);
            float var = qv * (1.f / NN) - mean * mean;
            float sc = g1[c] * rsqrtf(var + BN_EPS);
            st_sh[c] = sc;
            st_sh[DD2 + c] = bb1[c] - mean * sc;
        }
        __syncthreads();

        const int cb2 = wave * 32;  // this wave's 32-col slice of z2
        half8 sa[8], ta[8];
#pragma unroll
        for (int ks = 0; ks < 8; ks++) {
            const float* sp = st_sh + ks * 32 + q * 8;
            float4 sA = *(const float4*)(sp);
            float4 sB = *(const float4*)(sp + 4);
            float4 tA = *(const float4*)(sp + DD2);
            float4 tB = *(const float4*)(sp + DD2 + 4);
            sa[ks] = (half8){(_Float16)sA.x, (_Float16)sA.y, (_Float16)sA.z, (_Float16)sA.w,
                             (_Float16)sB.x, (_Float16)sB.y, (_Float16)sB.z, (_Float16)sB.w};
            ta[ks] = (half8){(_Float16)tA.x, (_Float16)tA.y, (_Float16)tA.z, (_Float16)tA.w,
                             (_Float16)tB.x, (_Float16)tB.y, (_Float16)tB.z, (_Float16)tB.w};
        }
        half8 wf2[2][8];
#pragma unroll
        for (int jm = 0; jm < 2; jm++) {
            const unsigned short* p = W2 + (size_t)(cb2 + jm * 16 + lr) * DD2 + q * 8;
#pragma unroll
            for (int ks = 0; ks < 8; ks++)
                wf2[jm][ks] = __builtin_bit_cast(half8, *(const int4*)(p + ks * 32));
        }
        float bi2[2][4];
#pragma unroll
        for (int jm = 0; jm < 2; jm++)
#pragma unroll
            for (int r = 0; r < 4; r++) bi2[jm][r] = b2[cb2 + jm * 16 + q * 4 + r];

        float s2[8], sq2[8];
#pragma unroll
        for (int k = 0; k < 8; k++) { s2[k] = 0.f; sq2[k] = 0.f; }

        for (int s = 0; s < 2; s++) {
            int t = blockIdx.x + s * GXF;
            if (t >= NT1) break;
            int row0 = t * 64;
            char* slot = ldsb + s * 32768;
            f32x4 acc[2][4];
#pragma unroll
            for (int jm = 0; jm < 2; jm++)
#pragma unroll
                for (int in = 0; in < 4; in++) acc[jm][in] = (f32x4){0.f, 0.f, 0.f, 0.f};
#pragma unroll
            for (int ks = 0; ks < 8; ks++) {
                half8 rf[4];
#pragma unroll
                for (int in = 0; in < 4; in++) {
                    int row = in * 16 + lr;
                    half8 z = *(const half8*)(slot + ((row * 512 + ks * 64 + q * 16) ^ swz));
                    rf[in] = bnrelu8(z, sa[ks], ta[ks]);
                }
#pragma unroll
                for (int jm = 0; jm < 2; jm++)
#pragma unroll
                    for (int in = 0; in < 4; in++)
                        acc[jm][in] = __builtin_amdgcn_mfma_f32_16x16x32_f16(
                            wf2[jm][ks], rf[in], acc[jm][in], 0, 0, 0);
            }
#pragma unroll
            for (int in = 0; in < 4; in++) {
                int row = row0 + in * 16 + lr;
                if (row < NN) {
#pragma unroll
                    for (int jm = 0; jm < 2; jm++) {
                        ushort4 o;
#pragma unroll
                        for (int r = 0; r < 4; r++) {
                            float v = acc[jm][in][r] + bi2[jm][r];
                            ((unsigned short*)&o)[r] = f2h_bits(v);
                            s2[jm * 4 + r] += v;
                            sq2[jm * 4 + r] += v * v;
                        }
                        *(ushort4*)(z2 + (size_t)row * DD + cb2 + jm * 16 + q * 4) = o;
                    }
                }
            }
        }
#pragma unroll
        for (int k = 0; k < 8; k++) {
            float a = s2[k], b = sq2[k];
#pragma unroll
            for (int m = 1; m < 16; m <<= 1) {
                a += __shfl_xor(a, m);
                b += __shfl_xor(b, m);
            }
            if (lr == 0) {
                int c = cb2 + (k >> 2) * 16 + q * 4 + (k & 3);
                unsafeAtomicAdd(&stats2[c], a);
                unsafeAtomicAdd(&stats2[DD + c], b);
            }
        }
    }
}

// ---------------- BN apply 2, last layer only: z2 fp16 -> d_out fp32 (no relu) ---------------

__global__ void bnapply2_last_kernel(const unsigned short* __restrict__ z,
                                     const float* __restrict__ stats, const float* __restrict__ g,
                                     const float* __restrict__ bb, float* __restrict__ fout) {
    __shared__ float s_sh[DD], t_sh[DD];
    if (threadIdx.x < DD) {
        int c = threadIdx.x;
        float mean = stats[c] * (1.f / NN);
        float var = stats[DD + c] * (1.f / NN) - mean * mean;
        float sc = g[c] * rsqrtf(var + BN_EPS);
        s_sh[c] = sc;
        t_sh[c] = bb[c] - mean * sc;
    }
    __syncthreads();
    int i = (blockIdx.x * 256 + threadIdx.x) * 4;
    int c = i & 127;
    uint2 in = *(const uint2*)(z + i);
    float4 out;
    out.x = h2f((unsigned short)(in.x & 0xffff)) * s_sh[c] + t_sh[c];
    out.y = h2f((unsigned short)(in.x >> 16)) * s_sh[c + 1] + t_sh[c + 1];
    out.z = h2f((unsigned short)(in.y & 0xffff)) * s_sh[c + 2] + t_sh[c + 2];
    out.w = h2f((unsigned short)(in.y >> 16)) * s_sh[c + 3] + t_sh[c + 3];
    *(float4*)(fout + i) = out;
}

// ---------------- launch ----------------

extern "C" void kernel_launch(void* const* d_in, const int* in_sizes, int n_in,
                              void* d_out, int out_size, void* d_ws, size_t ws_size,
                              hipStream_t stream) {
    const int* x = (const int*)d_in[0];
    const int* edge_index = (const int*)d_in[1];
    const int* edge_attr = (const int*)d_in[2];
    const float* edge_weight = (const float*)d_in[3];
    const float* atom_emb = (const float*)d_in[4];
    const float* bond_emb = (const float*)d_in[5];
    const float* W1 = (const float*)d_in[6];
    const float* b1 = (const float*)d_in[7];
    const float* bn1_g = (const float*)d_in[8];
    const float* bn1_b = (const float*)d_in[9];
    const float* W2 = (const float*)d_in[10];
    const float* b2 = (const float*)d_in[11];
    const float* eps_p = (const float*)d_in[12];
    const float* bn_g = (const float*)d_in[13];
    const float* bn_b = (const float*)d_in[14];
    const int* srcv = edge_index;
    const int* dstv = edge_index + EE;

    char* p = (char*)d_ws;
    auto alloc = [&](size_t bytes) {
        void* r = (void*)p;
        p += (bytes + 255) & ~(size_t)255;
        return r;
    };
    // A1h padded to NT1*64 rows so fused kernel's tail-tile reads stay in-buffer
    unsigned short* h = (unsigned short*)alloc((size_t)NN * DD * 2);
    unsigned short* A1h = (unsigned short*)alloc((size_t)(NT1 * 64) * DD * 2);
    unsigned short* z2 = (unsigned short*)alloc((size_t)NN * DD * 2);
    uint2* edata = (uint2*)alloc((size_t)EE * 8);
    int* counts = (int*)alloc((size_t)NN * 4);
    int* row_ptr = (int*)alloc((size_t)(NN + 1) * 4);
    int* blksum = (int*)alloc(256 * 4);
    unsigned short* W1t = (unsigned short*)alloc((size_t)LL * DD * DD2 * 2);
    unsigned short* W2t = (unsigned short*)alloc((size_t)LL * DD * DD2 * 2);
    unsigned short* bsum = (unsigned short*)alloc((size_t)LL * 512 * DD * 2);
    // stats + barrier slots zeroed together, in-graph, so every replay resets them
    float* statsAll = (float*)alloc((size_t)(LL * 512 + LL * 256 + LL * 2) * 4);
    float* stats1Base = statsAll;
    float* stats2Base = statsAll + LL * 512;
    int* barriers = (int*)(statsAll + LL * 512 + LL * 256);

    // --- one-time prep ---
    hipMemsetAsync(counts, 0, (size_t)NN * 4, stream);
    hipMemsetAsync(statsAll, 0, (size_t)(LL * 512 + LL * 256 + LL * 2) * 4, stream);
    hist_kernel<<<(EE + 255) / 256, 256, 0, stream>>>(dstv, counts);
    int nblk = (NN + 255) / 256;
    scan1_kernel<<<nblk, 256, 0, stream>>>(counts, row_ptr, blksum);
    scan2_kernel<<<1, 256, 0, stream>>>(blksum, nblk);
    scan3_kernel<<<nblk, 256, 0, stream>>>(row_ptr, blksum);
    hipMemsetAsync(counts, 0, (size_t)NN * 4, stream);
    scatter_kernel<<<(EE + 255) / 256, 256, 0, stream>>>(dstv, srcv, edge_attr, edge_weight,
                                                         row_ptr, counts, edata);
    prep_tables_kernel<<<(2 * LL * DD * DD2 + LL * 512 * DD + 255) / 256, 256, 0, stream>>>(
        W1, W2, bond_emb, W1t, W2t, bsum);
    init_h_kernel<<<NN / 8, 256, 0, stream>>>(x, atom_emb, h);

    for (int l = 0; l < LL; l++) {
        float* stats1 = stats1Base + l * 512;
        float* stats2 = stats2Base + l * 256;
        const unsigned short* bsum_l = bsum + (size_t)l * 512 * DD;

        if (l == 0) {
            agg_kernel<false><<<NN / 8, 256, 0, stream>>>(h, nullptr, nullptr, nullptr, row_ptr,
                                                          edata, bsum_l, eps_p + l, A1h);
        } else {
            agg_kernel<true><<<NN / 8, 256, 0, stream>>>(
                z2, stats2Base + (l - 1) * 256, bn_g + (l - 1) * DD, bn_b + (l - 1) * DD, row_ptr,
                edata, bsum_l, eps_p + l, A1h);
        }

        fused_mlp_kernel<<<GXF, 256, 0, stream>>>(
            A1h, W1t + (size_t)l * DD * DD2, b1 + l * DD2, W2t + (size_t)l * DD * DD2,
            b2 + l * DD, bn1_g + l * DD2, bn1_b + l * DD2, z2, stats1, stats2, barriers + l * 2);
    }

    bnapply2_last_kernel<<<NN * DD / 1024, 256, 0, stream>>>(
        z2, stats2Base + (LL - 1) * 256, bn_g + (LL - 1) * DD, bn_b + (LL - 1) * DD,
        (float*)d_out);
}

// Round 5
// 1047.203 us; speedup vs baseline: 1.1660x; 1.1270x over previous
//
#include <hip/hip_runtime.h>

#define NN 50000
#define EE 600000
#define DD 128
#define DD2 256
#define LL 5
#define BN_EPS 1e-5f
#define GXF 512
#define NT1 782  // ceil(NN/64) row-tiles of 64

typedef __attribute__((ext_vector_type(8))) _Float16 half8;
typedef __attribute__((ext_vector_type(4))) float f32x4;

__device__ inline unsigned short f2h_bits(float f) {
    _Float16 h = (_Float16)f;  // RTNE
    return __builtin_bit_cast(unsigned short, h);
}
__device__ inline float h2f(unsigned short u) {
    return (float)__builtin_bit_cast(_Float16, u);
}
__device__ inline half8 bnrelu8(half8 v, half8 s, half8 t) {
    half8 r = v * s + t;
#pragma unroll
    for (int k = 0; k < 8; k++) r[k] = (r[k] > (_Float16)0) ? r[k] : (_Float16)0;
    return r;
}

// Software grid barrier. Grid=512 == 256CU x 2 blocks/CU (launch_bounds(256,2), 66KB LDS
// caps at 2/CU), so all blocks are co-resident and a spin barrier is deadlock-free.
// R5: ALL cache-maintenance removed. R4's barrier used __threadfence (seq_cst agent fence =
// per-block L2 writeback+invalidate) and per-poll-iteration ACQUIRE loads (= L2 invalidate
// every ~0.4us per spinning block) -> continuous XCD-L2 wb/inv storm, 169us idle dispatches
// with MfmaUtil 1.5%. The stats atomics already execute at the coherence point (beyond the
// XCD L2 — proven cross-XCD-correct by the split-kernel baseline), and readers use sc1
// relaxed atomic loads that bypass the local L2, so the ONLY ordering needed is
// "my wave's atomic adds acked before arrival" = s_waitcnt vmcnt(0). Everything relaxed.
__device__ inline void grid_barrier(int* bar) {
    asm volatile("s_waitcnt vmcnt(0)" ::: "memory");  // per-wave drain of stats atomics
    __syncthreads();
    if (threadIdx.x == 0) {
        int t = __hip_atomic_fetch_add(&bar[0], 1, __ATOMIC_RELAXED, __HIP_MEMORY_SCOPE_AGENT);
        if (t == GXF - 1) {
            __hip_atomic_store(&bar[1], 1, __ATOMIC_RELAXED, __HIP_MEMORY_SCOPE_AGENT);
        } else {
            while (__hip_atomic_load(&bar[1], __ATOMIC_RELAXED, __HIP_MEMORY_SCOPE_AGENT) == 0) {
                __builtin_amdgcn_s_sleep(8);
            }
        }
    }
    __syncthreads();
}

// ---------------- CSR build ----------------

__global__ void hist_kernel(const int* __restrict__ dst, int* __restrict__ counts) {
    int e = blockIdx.x * blockDim.x + threadIdx.x;
    if (e < EE) atomicAdd(&counts[dst[e]], 1);
}

__global__ void scan1_kernel(const int* __restrict__ counts, int* __restrict__ row_ptr,
                             int* __restrict__ blksum) {
    __shared__ int tmp[256];
    int i = blockIdx.x * 256 + threadIdx.x;
    int v = (i < NN) ? counts[i] : 0;
    tmp[threadIdx.x] = v;
    __syncthreads();
    for (int off = 1; off < 256; off <<= 1) {
        int x = 0;
        if (threadIdx.x >= off) x = tmp[threadIdx.x - off];
        __syncthreads();
        if (threadIdx.x >= off) tmp[threadIdx.x] += x;
        __syncthreads();
    }
    if (i < NN) row_ptr[i] = tmp[threadIdx.x] - v;
    if (threadIdx.x == 255) blksum[blockIdx.x] = tmp[255];
}

__global__ void scan2_kernel(int* __restrict__ blksum, int nblocks) {
    __shared__ int tmp[256];
    int v = (threadIdx.x < nblocks) ? blksum[threadIdx.x] : 0;
    tmp[threadIdx.x] = v;
    __syncthreads();
    for (int off = 1; off < 256; off <<= 1) {
        int x = 0;
        if (threadIdx.x >= off) x = tmp[threadIdx.x - off];
        __syncthreads();
        if (threadIdx.x >= off) tmp[threadIdx.x] += x;
        __syncthreads();
    }
    blksum[threadIdx.x] = tmp[threadIdx.x] - v;
}

__global__ void scan3_kernel(int* __restrict__ row_ptr, const int* __restrict__ blksum) {
    int i = blockIdx.x * 256 + threadIdx.x;
    if (i < NN) row_ptr[i] += blksum[blockIdx.x];
    if (i == 0) row_ptr[NN] = EE;
}

// scatter + pack edge data: edata[p] = {src, cid | w_fp16<<16}
__global__ void scatter_kernel(const int* __restrict__ dst, const int* __restrict__ src,
                               const int* __restrict__ edge_attr, const float* __restrict__ ew,
                               const int* __restrict__ row_ptr, int* __restrict__ cursor,
                               uint2* __restrict__ edata) {
    int e = blockIdx.x * blockDim.x + threadIdx.x;
    if (e < EE) {
        int d = dst[e];
        int p = row_ptr[d] + atomicAdd(&cursor[d], 1);
        int cid = edge_attr[3 * e + 0] + 8 * edge_attr[3 * e + 1] + 64 * edge_attr[3 * e + 2];
        uint2 v;
        v.x = (unsigned)src[e];
        v.y = (unsigned)cid | ((unsigned)f2h_bits(ew[e]) << 16);
        edata[p] = v;
    }
}

// ---------------- table prep: W1t, W2t (fp16, [M][K]) + combined bond table (fp16) ------------

__global__ void prep_tables_kernel(const float* __restrict__ W1, const float* __restrict__ W2,
                                   const float* __restrict__ bond_emb,
                                   unsigned short* __restrict__ W1t,
                                   unsigned short* __restrict__ W2t,
                                   unsigned short* __restrict__ bsum) {
    const int NW = LL * DD * DD2;  // 163840
    int idx = blockIdx.x * 256 + threadIdx.x;
    if (idx < NW) {
        int l = idx / (DD * DD2);
        int rem = idx - l * DD * DD2;
        int k = rem / DD2, m = rem - k * DD2;  // W1: [L][128][256]
        W1t[(size_t)l * DD * DD2 + (size_t)m * DD + k] = f2h_bits(W1[idx]);
    } else if (idx < 2 * NW) {
        int j = idx - NW;
        int l = j / (DD * DD2);
        int rem = j - l * DD * DD2;
        int k = rem / DD, m = rem - k * DD;  // W2: [L][256][128]
        W2t[(size_t)l * DD * DD2 + (size_t)m * DD2 + k] = f2h_bits(W2[j]);
    } else if (idx < 2 * NW + LL * 512 * DD) {
        int j = idx - 2 * NW;
        int l = j >> 16;  // 512*128
        int rem = j & 65535;
        int cid = rem >> 7, d = rem & 127;
        int a0 = cid & 7, a1 = (cid >> 3) & 7, a2 = cid >> 6;
        const float* base = bond_emb + (size_t)l * 3 * 8 * DD;
        bsum[j] = f2h_bits(base[a0 * DD + d] + base[(8 + a1) * DD + d] + base[(16 + a2) * DD + d]);
    }
}

// ---------------- node init (fp16 h0) ----------------

__global__ void init_h_kernel(const int* __restrict__ x, const float* __restrict__ atom_emb,
                              unsigned short* __restrict__ h) {
    int n = blockIdx.x * 8 + (threadIdx.x >> 5);
    int lane = threadIdx.x & 31;
    float a0 = 0.f, a1 = 0.f, a2 = 0.f, a3 = 0.f;
#pragma unroll
    for (int f = 0; f < 9; f++) {
        int idx = x[n * 9 + f];
        const float4 v = *(const float4*)(atom_emb + ((size_t)(f * 64 + idx) * DD) + lane * 4);
        a0 += v.x; a1 += v.y; a2 += v.z; a3 += v.w;
    }
    ushort4 o;
    o.x = f2h_bits(a0); o.y = f2h_bits(a1); o.z = f2h_bits(a2); o.w = f2h_bits(a3);
    *(ushort4*)(h + (size_t)n * DD + lane * 4) = o;
}

// ---------------- edge aggregate → A fp16, optional fused BN2+relu on gathered rows ----------

template <bool FUSE>
__global__ void agg_kernel(const unsigned short* __restrict__ hsrc,
                           const float* __restrict__ stats, const float* __restrict__ g,
                           const float* __restrict__ bb, const int* __restrict__ row_ptr,
                           const uint2* __restrict__ edata,
                           const unsigned short* __restrict__ bsum_l,
                           const float* __restrict__ eps_ptr, unsigned short* __restrict__ Aout) {
    int n = blockIdx.x * 8 + (threadIdx.x >> 5);
    int lane = threadIdx.x & 31;
    int c0 = lane * 4;

    float bs[4] = {1.f, 1.f, 1.f, 1.f}, bt[4] = {0.f, 0.f, 0.f, 0.f};
    if (FUSE) {
        float4 sm = *(const float4*)(stats + c0);
        float4 sq = *(const float4*)(stats + DD + c0);
        float4 gg = *(const float4*)(g + c0);
        float4 bv = *(const float4*)(bb + c0);
        float mv[4] = {sm.x, sm.y, sm.z, sm.w};
        float qv[4] = {sq.x, sq.y, sq.z, sq.w};
        float gv[4] = {gg.x, gg.y, gg.z, gg.w};
        float bbv[4] = {bv.x, bv.y, bv.z, bv.w};
#pragma unroll
        for (int k = 0; k < 4; k++) {
            float mean = mv[k] * (1.f / NN);
            float var = qv[k] * (1.f / NN) - mean * mean;
            bs[k] = gv[k] * rsqrtf(var + BN_EPS);
            bt[k] = bbv[k] - mean * bs[k];
        }
    }

    auto accum = [&](uint2 ed, uint2 hz, uint2 bz, float* acc) {
        float w = h2f((unsigned short)(ed.y >> 16));
        unsigned int hw[2] = {hz.x, hz.y}, bw[2] = {bz.x, bz.y};
#pragma unroll
        for (int k = 0; k < 2; k++) {
            float hv0 = h2f((unsigned short)(hw[k] & 0xffff));
            float hv1 = h2f((unsigned short)(hw[k] >> 16));
            if (FUSE) {
                hv0 = fmaxf(hv0 * bs[2 * k] + bt[2 * k], 0.f);
                hv1 = fmaxf(hv1 * bs[2 * k + 1] + bt[2 * k + 1], 0.f);
            }
            float m0 = fmaxf(hv0 + h2f((unsigned short)(bw[k] & 0xffff)), 0.f);
            float m1 = fmaxf(hv1 + h2f((unsigned short)(bw[k] >> 16)), 0.f);
            acc[2 * k] += m0 * w;
            acc[2 * k + 1] += m1 * w;
        }
    };

    int beg = row_ptr[n], end = row_ptr[n + 1];
    float acc[4] = {0.f, 0.f, 0.f, 0.f};
    int i = beg;
    for (; i + 4 <= end; i += 4) {
        uint2 e0 = edata[i], e1 = edata[i + 1], e2 = edata[i + 2], e3 = edata[i + 3];
        uint2 h0 = *(const uint2*)(hsrc + (size_t)e0.x * DD + c0);
        uint2 b0 = *(const uint2*)(bsum_l + (size_t)(e0.y & 0xffff) * DD + c0);
        uint2 h1 = *(const uint2*)(hsrc + (size_t)e1.x * DD + c0);
        uint2 b1 = *(const uint2*)(bsum_l + (size_t)(e1.y & 0xffff) * DD + c0);
        uint2 h2 = *(const uint2*)(hsrc + (size_t)e2.x * DD + c0);
        uint2 b2 = *(const uint2*)(bsum_l + (size_t)(e2.y & 0xffff) * DD + c0);
        uint2 h3 = *(const uint2*)(hsrc + (size_t)e3.x * DD + c0);
        uint2 b3 = *(const uint2*)(bsum_l + (size_t)(e3.y & 0xffff) * DD + c0);
        accum(e0, h0, b0, acc);
        accum(e1, h1, b1, acc);
        accum(e2, h2, b2, acc);
        accum(e3, h3, b3, acc);
    }
    for (; i < end; i++) {
        uint2 e0 = edata[i];
        uint2 h0 = *(const uint2*)(hsrc + (size_t)e0.x * DD + c0);
        uint2 b0 = *(const uint2*)(bsum_l + (size_t)(e0.y & 0xffff) * DD + c0);
        accum(e0, h0, b0, acc);
    }

    float eps1 = 1.f + eps_ptr[0];
    uint2 hz = *(const uint2*)(hsrc + (size_t)n * DD + c0);
    unsigned int hw[2] = {hz.x, hz.y};
    float self[4];
#pragma unroll
    for (int k = 0; k < 2; k++) {
        float hv0 = h2f((unsigned short)(hw[k] & 0xffff));
        float hv1 = h2f((unsigned short)(hw[k] >> 16));
        if (FUSE) {
            hv0 = fmaxf(hv0 * bs[2 * k] + bt[2 * k], 0.f);
            hv1 = fmaxf(hv1 * bs[2 * k + 1] + bt[2 * k + 1], 0.f);
        }
        self[2 * k] = hv0;
        self[2 * k + 1] = hv1;
    }
    ushort4 o;
    o.x = f2h_bits(eps1 * self[0] + acc[0]);
    o.y = f2h_bits(eps1 * self[1] + acc[1]);
    o.z = f2h_bits(eps1 * self[2] + acc[2]);
    o.w = f2h_bits(eps1 * self[3] + acc[3]);
    *(ushort4*)(Aout + (size_t)n * DD + c0) = o;
}

// ---------------- fused GEMM1 + BN1 + relu + GEMM2, z1 resident in LDS ----------------
// Persistent kernel, 512 blocks = exactly 2/CU (launch_bounds(256,2), 66KB LDS).
// Phase 1: z1 tile (64 rows x 256 cols) = A @ W1 + b1 -> LDS fp16 (+ col stats atomics).
// Software grid barrier (fence-free, see grid_barrier). Phase 2: BN1 scale/shift broadcast
// via LDS, relu on LDS fragments, z2 = z1bn @ W2 + b2 -> global (+ stats2).
// MFMA operands swapped (A-op = weight frags, B-op = row frags) so the 4 acc elements per
// fragment are 4 CONSECUTIVE COLUMNS -> packed ushort4 LDS writes / global stores.
// LDS swizzle: phys = (row*512 + colbyte) ^ ((lr&7)<<4).
// R3 fix: stats1 read ONCE per block into st_sh via sc1 relaxed atomic loads (bypass
// XCD-local L2 -> no stale values from a previous graph replay, no invalidate traffic).

__global__ __launch_bounds__(256, 2) void fused_mlp_kernel(
    const unsigned short* __restrict__ A, const unsigned short* __restrict__ W1,
    const float* __restrict__ b1, const unsigned short* __restrict__ W2,
    const float* __restrict__ b2, const float* __restrict__ g1,
    const float* __restrict__ bb1, unsigned short* __restrict__ z2,
    float* __restrict__ stats1, float* __restrict__ stats2, int* bar) {
    __shared__ __align__(16) char ldsb[65536];  // 2 slots x [64 rows][256 cols] fp16
    __shared__ __align__(16) float st_sh[2 * DD2];  // BN1 scale/shift broadcast
    const int lane = threadIdx.x & 63;
    const int wave = threadIdx.x >> 6;
    const int lr = lane & 15;
    const int q = lane >> 4;
    const int swz = (lr & 7) << 4;

    // ---- phase 1 ----
    {
        const int wcol = wave * 64;  // this wave's 64-col slice of z1
        half8 wf[4][4];
#pragma unroll
        for (int jm = 0; jm < 4; jm++) {
            const unsigned short* p = W1 + (size_t)(wcol + jm * 16 + lr) * DD + q * 8;
#pragma unroll
            for (int ks = 0; ks < 4; ks++)
                wf[jm][ks] = __builtin_bit_cast(half8, *(const int4*)(p + ks * 32));
        }
        float bi[4][4];
#pragma unroll
        for (int jm = 0; jm < 4; jm++)
#pragma unroll
            for (int r = 0; r < 4; r++) bi[jm][r] = b1[wcol + jm * 16 + q * 4 + r];

        float s1[16], sq1[16];
#pragma unroll
        for (int k = 0; k < 16; k++) { s1[k] = 0.f; sq1[k] = 0.f; }

        for (int s = 0; s < 2; s++) {
            int t = blockIdx.x + s * GXF;
            if (t >= NT1) break;
            int row0 = t * 64;
            // OOB rows (>=NN, <50048) read benign ws poison; results never stored/counted
            const unsigned short* ap0 = A + (size_t)(row0 + lr) * DD + q * 8;
            f32x4 acc[4][4];
#pragma unroll
            for (int jm = 0; jm < 4; jm++)
#pragma unroll
                for (int in = 0; in < 4; in++) acc[jm][in] = (f32x4){0.f, 0.f, 0.f, 0.f};
#pragma unroll
            for (int ks = 0; ks < 4; ks++) {
                half8 rf[4];
#pragma unroll
                for (int in = 0; in < 4; in++)
                    rf[in] = __builtin_bit_cast(
                        half8, *(const int4*)(ap0 + (size_t)(in * 16) * DD + ks * 32));
#pragma unroll
                for (int jm = 0; jm < 4; jm++)
#pragma unroll
                    for (int in = 0; in < 4; in++)
                        acc[jm][in] = __builtin_amdgcn_mfma_f32_16x16x32_f16(
                            wf[jm][ks], rf[in], acc[jm][in], 0, 0, 0);
            }
            char* slot = ldsb + s * 32768;
#pragma unroll
            for (int in = 0; in < 4; in++) {
                int row = in * 16 + lr;
                bool rv = (row0 + row) < NN;
                int rbase = row * 512 + wave * 128;  // wave's 64-col (128 B) offset
#pragma unroll
                for (int jm = 0; jm < 4; jm++) {
                    ushort4 o;
#pragma unroll
                    for (int r = 0; r < 4; r++) {
                        float v = acc[jm][in][r] + bi[jm][r];
                        ((unsigned short*)&o)[r] = f2h_bits(v);
                        if (rv) {
                            s1[jm * 4 + r] += v;
                            sq1[jm * 4 + r] += v * v;
                        }
                    }
                    *(ushort4*)(slot + ((rbase + jm * 32 + q * 8) ^ swz)) = o;
                }
            }
        }
#pragma unroll
        for (int k = 0; k < 16; k++) {
            float a = s1[k], b = sq1[k];
#pragma unroll
            for (int m = 1; m < 16; m <<= 1) {
                a += __shfl_xor(a, m);
                b += __shfl_xor(b, m);
            }
            if (lr == 0) {
                int c = wcol + (k >> 2) * 16 + q * 4 + (k & 3);
                unsafeAtomicAdd(&stats1[c], a);
                unsafeAtomicAdd(&stats1[DD2 + c], b);
            }
        }
    }

    grid_barrier(bar);

    // ---- phase 2 ----
    {
        // BN1 scale/shift: one coalesced pass per block into LDS (R3 fix)
        for (int c = threadIdx.x; c < DD2; c += 256) {
            float sv = __hip_atomic_load(&stats1[c], __ATOMIC_RELAXED, __HIP_MEMORY_SCOPE_AGENT);
            float qv =
                __hip_atomic_load(&stats1[DD2 + c], __ATOMIC_RELAXED, __HIP_MEMORY_SCOPE_AGENT);
            float mean = sv * (1.f / NN);
            float var = qv * (1.f / NN) - mean * mean;
            float sc = g1[c] * rsqrtf(var + BN_EPS);
            st_sh[c] = sc;
            st_sh[DD2 + c] = bb1[c] - mean * sc;
        }
        __syncthreads();

        const int cb2 = wave * 32;  // this wave's 32-col slice of z2
        half8 sa[8], ta[8];
#pragma unroll
        for (int ks = 0; ks < 8; ks++) {
            const float* sp = st_sh + ks * 32 + q * 8;
            float4 sA = *(const float4*)(sp);
            float4 sB = *(const float4*)(sp + 4);
            float4 tA = *(const float4*)(sp + DD2);
            float4 tB = *(const float4*)(sp + DD2 + 4);
            sa[ks] = (half8){(_Float16)sA.x, (_Float16)sA.y, (_Float16)sA.z, (_Float16)sA.w,
                             (_Float16)sB.x, (_Float16)sB.y, (_Float16)sB.z, (_Float16)sB.w};
            ta[ks] = (half8){(_Float16)tA.x, (_Float16)tA.y, (_Float16)tA.z, (_Float16)tA.w,
                             (_Float16)tB.x, (_Float16)tB.y, (_Float16)tB.z, (_Float16)tB.w};
        }
        half8 wf2[2][8];
#pragma unroll
        for (int jm = 0; jm < 2; jm++) {
            const unsigned short* p = W2 + (size_t)(cb2 + jm * 16 + lr) * DD2 + q * 8;
#pragma unroll
            for (int ks = 0; ks < 8; ks++)
                wf2[jm][ks] = __builtin_bit_cast(half8, *(const int4*)(p + ks * 32));
        }
        float bi2[2][4];
#pragma unroll
        for (int jm = 0; jm < 2; jm++)
#pragma unroll
            for (int r = 0; r < 4; r++) bi2[jm][r] = b2[cb2 + jm * 16 + q * 4 + r];

        float s2[8], sq2[8];
#pragma unroll
        for (int k = 0; k < 8; k++) { s2[k] = 0.f; sq2[k] = 0.f; }

        for (int s = 0; s < 2; s++) {
            int t = blockIdx.x + s * GXF;
            if (t >= NT1) break;
            int row0 = t * 64;
            char* slot = ldsb + s * 32768;
            f32x4 acc[2][4];
#pragma unroll
            for (int jm = 0; jm < 2; jm++)
#pragma unroll
                for (int in = 0; in < 4; in++) acc[jm][in] = (f32x4){0.f, 0.f, 0.f, 0.f};
#pragma unroll
            for (int ks = 0; ks < 8; ks++) {
                half8 rf[4];
#pragma unroll
                for (int in = 0; in < 4; in++) {
                    int row = in * 16 + lr;
                    half8 z = *(const half8*)(slot + ((row * 512 + ks * 64 + q * 16) ^ swz));
                    rf[in] = bnrelu8(z, sa[ks], ta[ks]);
                }
#pragma unroll
                for (int jm = 0; jm < 2; jm++)
#pragma unroll
                    for (int in = 0; in < 4; in++)
                        acc[jm][in] = __builtin_amdgcn_mfma_f32_16x16x32_f16(
                            wf2[jm][ks], rf[in], acc[jm][in], 0, 0, 0);
            }
#pragma unroll
            for (int in = 0; in < 4; in++) {
                int row = row0 + in * 16 + lr;
                if (row < NN) {
#pragma unroll
                    for (int jm = 0; jm < 2; jm++) {
                        ushort4 o;
#pragma unroll
                        for (int r = 0; r < 4; r++) {
                            float v = acc[jm][in][r] + bi2[jm][r];
                            ((unsigned short*)&o)[r] = f2h_bits(v);
                            s2[jm * 4 + r] += v;
                            sq2[jm * 4 + r] += v * v;
                        }
                        *(ushort4*)(z2 + (size_t)row * DD + cb2 + jm * 16 + q * 4) = o;
                    }
                }
            }
        }
#pragma unroll
        for (int k = 0; k < 8; k++) {
            float a = s2[k], b = sq2[k];
#pragma unroll
            for (int m = 1; m < 16; m <<= 1) {
                a += __shfl_xor(a, m);
                b += __shfl_xor(b, m);
            }
            if (lr == 0) {
                int c = cb2 + (k >> 2) * 16 + q * 4 + (k & 3);
                unsafeAtomicAdd(&stats2[c], a);
                unsafeAtomicAdd(&stats2[DD + c], b);
            }
        }
    }
}

// ---------------- BN apply 2, last layer only: z2 fp16 -> d_out fp32 (no relu) ---------------

__global__ void bnapply2_last_kernel(const unsigned short* __restrict__ z,
                                     const float* __restrict__ stats, const float* __restrict__ g,
                                     const float* __restrict__ bb, float* __restrict__ fout) {
    __shared__ float s_sh[DD], t_sh[DD];
    if (threadIdx.x < DD) {
        int c = threadIdx.x;
        float mean = stats[c] * (1.f / NN);
        float var = stats[DD + c] * (1.f / NN) - mean * mean;
        float sc = g[c] * rsqrtf(var + BN_EPS);
        s_sh[c] = sc;
        t_sh[c] = bb[c] - mean * sc;
    }
    __syncthreads();
    int i = (blockIdx.x * 256 + threadIdx.x) * 4;
    int c = i & 127;
    uint2 in = *(const uint2*)(z + i);
    float4 out;
    out.x = h2f((unsigned short)(in.x & 0xffff)) * s_sh[c] + t_sh[c];
    out.y = h2f((unsigned short)(in.x >> 16)) * s_sh[c + 1] + t_sh[c + 1];
    out.z = h2f((unsigned short)(in.y & 0xffff)) * s_sh[c + 2] + t_sh[c + 2];
    out.w = h2f((unsigned short)(in.y >> 16)) * s_sh[c + 3] + t_sh[c + 3];
    *(float4*)(fout + i) = out;
}

// ---------------- launch ----------------

extern "C" void kernel_launch(void* const* d_in, const int* in_sizes, int n_in,
                              void* d_out, int out_size, void* d_ws, size_t ws_size,
                              hipStream_t stream) {
    const int* x = (const int*)d_in[0];
    const int* edge_index = (const int*)d_in[1];
    const int* edge_attr = (const int*)d_in[2];
    const float* edge_weight = (const float*)d_in[3];
    const float* atom_emb = (const float*)d_in[4];
    const float* bond_emb = (const float*)d_in[5];
    const float* W1 = (const float*)d_in[6];
    const float* b1 = (const float*)d_in[7];
    const float* bn1_g = (const float*)d_in[8];
    const float* bn1_b = (const float*)d_in[9];
    const float* W2 = (const float*)d_in[10];
    const float* b2 = (const float*)d_in[11];
    const float* eps_p = (const float*)d_in[12];
    const float* bn_g = (const float*)d_in[13];
    const float* bn_b = (const float*)d_in[14];
    const int* srcv = edge_index;
    const int* dstv = edge_index + EE;

    char* p = (char*)d_ws;
    auto alloc = [&](size_t bytes) {
        void* r = (void*)p;
        p += (bytes + 255) & ~(size_t)255;
        return r;
    };
    // A1h padded to NT1*64 rows so fused kernel's tail-tile reads stay in-buffer
    unsigned short* h = (unsigned short*)alloc((size_t)NN * DD * 2);
    unsigned short* A1h = (unsigned short*)alloc((size_t)(NT1 * 64) * DD * 2);
    unsigned short* z2 = (unsigned short*)alloc((size_t)NN * DD * 2);
    uint2* edata = (uint2*)alloc((size_t)EE * 8);
    int* counts = (int*)alloc((size_t)NN * 4);
    int* row_ptr = (int*)alloc((size_t)(NN + 1) * 4);
    int* blksum = (int*)alloc(256 * 4);
    unsigned short* W1t = (unsigned short*)alloc((size_t)LL * DD * DD2 * 2);
    unsigned short* W2t = (unsigned short*)alloc((size_t)LL * DD * DD2 * 2);
    unsigned short* bsum = (unsigned short*)alloc((size_t)LL * 512 * DD * 2);
    // stats + barrier slots zeroed together, in-graph, so every replay resets them
    float* statsAll = (float*)alloc((size_t)(LL * 512 + LL * 256 + LL * 2) * 4);
    float* stats1Base = statsAll;
    float* stats2Base = statsAll + LL * 512;
    int* barriers = (int*)(statsAll + LL * 512 + LL * 256);

    // --- one-time prep ---
    hipMemsetAsync(counts, 0, (size_t)NN * 4, stream);
    hipMemsetAsync(statsAll, 0, (size_t)(LL * 512 + LL * 256 + LL * 2) * 4, stream);
    hist_kernel<<<(EE + 255) / 256, 256, 0, stream>>>(dstv, counts);
    int nblk = (NN + 255) / 256;
    scan1_kernel<<<nblk, 256, 0, stream>>>(counts, row_ptr, blksum);
    scan2_kernel<<<1, 256, 0, stream>>>(blksum, nblk);
    scan3_kernel<<<nblk, 256, 0, stream>>>(row_ptr, blksum);
    hipMemsetAsync(counts, 0, (size_t)NN * 4, stream);
    scatter_kernel<<<(EE + 255) / 256, 256, 0, stream>>>(dstv, srcv, edge_attr, edge_weight,
                                                         row_ptr, counts, edata);
    prep_tables_kernel<<<(2 * LL * DD * DD2 + LL * 512 * DD + 255) / 256, 256, 0, stream>>>(
        W1, W2, bond_emb, W1t, W2t, bsum);
    init_h_kernel<<<NN / 8, 256, 0, stream>>>(x, atom_emb, h);

    for (int l = 0; l < LL; l++) {
        float* stats1 = stats1Base + l * 512;
        float* stats2 = stats2Base + l * 256;
        const unsigned short* bsum_l = bsum + (size_t)l * 512 * DD;

        if (l == 0) {
            agg_kernel<false><<<NN / 8, 256, 0, stream>>>(h, nullptr, nullptr, nullptr, row_ptr,
                                                          edata, bsum_l, eps_p + l, A1h);
        } else {
            agg_kernel<true><<<NN / 8, 256, 0, stream>>>(
                z2, stats2Base + (l - 1) * 256, bn_g + (l - 1) * DD, bn_b + (l - 1) * DD, row_ptr,
                edata, bsum_l, eps_p + l, A1h);
        }

        fused_mlp_kernel<<<GXF, 256, 0, stream>>>(
            A1h, W1t + (size_t)l * DD * DD2, b1 + l * DD2, W2t + (size_t)l * DD * DD2,
            b2 + l * DD, bn1_g + l * DD2, bn1_b + l * DD2, z2, stats1, stats2, barriers + l * 2);
    }

    bnapply2_last_kernel<<<NN * DD / 1024, 256, 0, stream>>>(
        z2, stats2Base + (LL - 1) * 256, bn_g + (LL - 1) * DD, bn_b + (LL - 1) * DD,
        (float*)d_out);
}

// Round 6
// 791.519 us; speedup vs baseline: 1.5427x; 1.3230x over previous
//
#include <hip/hip_runtime.h>

#define NN 50000
#define EE 600000
#define DD 128
#define DD2 256
#define LL 5
#define BN_EPS 1e-5f
#define GXF 512
#define NT1 782  // ceil(NN/64) row-tiles of 64
#define SPAD 16  // floats per padded stats slot = one 64B line

typedef __attribute__((ext_vector_type(8))) _Float16 half8;
typedef __attribute__((ext_vector_type(4))) float f32x4;

__device__ inline unsigned short f2h_bits(float f) {
    _Float16 h = (_Float16)f;  // RTNE
    return __builtin_bit_cast(unsigned short, h);
}
__device__ inline float h2f(unsigned short u) {
    return (float)__builtin_bit_cast(_Float16, u);
}
__device__ inline half8 bnrelu8(half8 v, half8 s, half8 t) {
    half8 r = v * s + t;
#pragma unroll
    for (int k = 0; k < 8; k++) r[k] = (r[k] > (_Float16)0) ? r[k] : (_Float16)0;
    return r;
}

// Stats layout (R6): every accumulator on its OWN 64B line. R5's 140us idle dispatches are
// explained by same-line atomic RMW serialization: 512 blocks x 512 stats adds = 262K fp32
// RMWs on 48 cache lines = 8192 serialized line-locked RMWs/line x ~15ns ~= 120us. Padding
// to 1 float/line turns this into 512 parallel 512-deep chains ~= 10us critical path.
// Layer region: 768 slots (stats1 sum[256] slots 0..255, sq slots 256..511;
// stats2 sum slots 512..639, sq slots 640..767), slot stride SPAD floats.

// Software grid barrier. Grid=512 == 256CU x 2 blocks/CU (launch_bounds(256,2), 66KB LDS
// caps at 2/CU) -> all blocks co-resident, spin is deadlock-free. Fence-free (R5): stats
// atomics complete at the coherence point; readers use sc1 loads; only ordering needed is
// "my adds acked before arrival" = s_waitcnt vmcnt(0).
// R6: hierarchical arrival — 8 padded sub-counters (64 blocks each) -> master -> flag,
// so the arrival RMW chain is 64 deep, not 512. bar layout (ints): sub[g] @ g*16,
// master @ 128, flag @ 144; per-layer stride 160.
__device__ inline void grid_barrier(int* bar) {
    asm volatile("s_waitcnt vmcnt(0)" ::: "memory");  // drain this block's stats atomics
    __syncthreads();
    if (threadIdx.x == 0) {
        int g = blockIdx.x & 7;
        bool done = false;
        int t = __hip_atomic_fetch_add(&bar[g * 16], 1, __ATOMIC_RELAXED,
                                       __HIP_MEMORY_SCOPE_AGENT);
        if (t == (GXF / 8) - 1) {  // last of my group
            int m = __hip_atomic_fetch_add(&bar[128], 1, __ATOMIC_RELAXED,
                                           __HIP_MEMORY_SCOPE_AGENT);
            if (m == 7) {  // last group
                __hip_atomic_store(&bar[144], 1, __ATOMIC_RELAXED, __HIP_MEMORY_SCOPE_AGENT);
                done = true;
            }
        }
        if (!done) {
            while (__hip_atomic_load(&bar[144], __ATOMIC_RELAXED, __HIP_MEMORY_SCOPE_AGENT) == 0)
                __builtin_amdgcn_s_sleep(8);
        }
    }
    __syncthreads();
}

// ---------------- CSR build ----------------

__global__ void hist_kernel(const int* __restrict__ dst, int* __restrict__ counts) {
    int e = blockIdx.x * blockDim.x + threadIdx.x;
    if (e < EE) atomicAdd(&counts[dst[e]], 1);
}

__global__ void scan1_kernel(const int* __restrict__ counts, int* __restrict__ row_ptr,
                             int* __restrict__ blksum) {
    __shared__ int tmp[256];
    int i = blockIdx.x * 256 + threadIdx.x;
    int v = (i < NN) ? counts[i] : 0;
    tmp[threadIdx.x] = v;
    __syncthreads();
    for (int off = 1; off < 256; off <<= 1) {
        int x = 0;
        if (threadIdx.x >= off) x = tmp[threadIdx.x - off];
        __syncthreads();
        if (threadIdx.x >= off) tmp[threadIdx.x] += x;
        __syncthreads();
    }
    if (i < NN) row_ptr[i] = tmp[threadIdx.x] - v;
    if (threadIdx.x == 255) blksum[blockIdx.x] = tmp[255];
}

__global__ void scan2_kernel(int* __restrict__ blksum, int nblocks) {
    __shared__ int tmp[256];
    int v = (threadIdx.x < nblocks) ? blksum[threadIdx.x] : 0;
    tmp[threadIdx.x] = v;
    __syncthreads();
    for (int off = 1; off < 256; off <<= 1) {
        int x = 0;
        if (threadIdx.x >= off) x = tmp[threadIdx.x - off];
        __syncthreads();
        if (threadIdx.x >= off) tmp[threadIdx.x] += x;
        __syncthreads();
    }
    blksum[threadIdx.x] = tmp[threadIdx.x] - v;
}

__global__ void scan3_kernel(int* __restrict__ row_ptr, const int* __restrict__ blksum) {
    int i = blockIdx.x * 256 + threadIdx.x;
    if (i < NN) row_ptr[i] += blksum[blockIdx.x];
    if (i == 0) row_ptr[NN] = EE;
}

// scatter + pack edge data: edata[p] = {src, cid | w_fp16<<16}
__global__ void scatter_kernel(const int* __restrict__ dst, const int* __restrict__ src,
                               const int* __restrict__ edge_attr, const float* __restrict__ ew,
                               const int* __restrict__ row_ptr, int* __restrict__ cursor,
                               uint2* __restrict__ edata) {
    int e = blockIdx.x * blockDim.x + threadIdx.x;
    if (e < EE) {
        int d = dst[e];
        int p = row_ptr[d] + atomicAdd(&cursor[d], 1);
        int cid = edge_attr[3 * e + 0] + 8 * edge_attr[3 * e + 1] + 64 * edge_attr[3 * e + 2];
        uint2 v;
        v.x = (unsigned)src[e];
        v.y = (unsigned)cid | ((unsigned)f2h_bits(ew[e]) << 16);
        edata[p] = v;
    }
}

// ---------------- table prep: W1t, W2t (fp16, [M][K]) + combined bond table (fp16) ------------

__global__ void prep_tables_kernel(const float* __restrict__ W1, const float* __restrict__ W2,
                                   const float* __restrict__ bond_emb,
                                   unsigned short* __restrict__ W1t,
                                   unsigned short* __restrict__ W2t,
                                   unsigned short* __restrict__ bsum) {
    const int NW = LL * DD * DD2;  // 163840
    int idx = blockIdx.x * 256 + threadIdx.x;
    if (idx < NW) {
        int l = idx / (DD * DD2);
        int rem = idx - l * DD * DD2;
        int k = rem / DD2, m = rem - k * DD2;  // W1: [L][128][256]
        W1t[(size_t)l * DD * DD2 + (size_t)m * DD + k] = f2h_bits(W1[idx]);
    } else if (idx < 2 * NW) {
        int j = idx - NW;
        int l = j / (DD * DD2);
        int rem = j - l * DD * DD2;
        int k = rem / DD, m = rem - k * DD;  // W2: [L][256][128]
        W2t[(size_t)l * DD * DD2 + (size_t)m * DD2 + k] = f2h_bits(W2[j]);
    } else if (idx < 2 * NW + LL * 512 * DD) {
        int j = idx - 2 * NW;
        int l = j >> 16;  // 512*128
        int rem = j & 65535;
        int cid = rem >> 7, d = rem & 127;
        int a0 = cid & 7, a1 = (cid >> 3) & 7, a2 = cid >> 6;
        const float* base = bond_emb + (size_t)l * 3 * 8 * DD;
        bsum[j] = f2h_bits(base[a0 * DD + d] + base[(8 + a1) * DD + d] + base[(16 + a2) * DD + d]);
    }
}

// ---------------- node init (fp16 h0) ----------------

__global__ void init_h_kernel(const int* __restrict__ x, const float* __restrict__ atom_emb,
                              unsigned short* __restrict__ h) {
    int n = blockIdx.x * 8 + (threadIdx.x >> 5);
    int lane = threadIdx.x & 31;
    float a0 = 0.f, a1 = 0.f, a2 = 0.f, a3 = 0.f;
#pragma unroll
    for (int f = 0; f < 9; f++) {
        int idx = x[n * 9 + f];
        const float4 v = *(const float4*)(atom_emb + ((size_t)(f * 64 + idx) * DD) + lane * 4);
        a0 += v.x; a1 += v.y; a2 += v.z; a3 += v.w;
    }
    ushort4 o;
    o.x = f2h_bits(a0); o.y = f2h_bits(a1); o.z = f2h_bits(a2); o.w = f2h_bits(a3);
    *(ushort4*)(h + (size_t)n * DD + lane * 4) = o;
}

// ---------------- edge aggregate → A fp16, optional fused BN2+relu on gathered rows ----------
// FUSE: stats = PADDED layer region of previous layer (stats2 slots 512.. / 640..).

template <bool FUSE>
__global__ void agg_kernel(const unsigned short* __restrict__ hsrc,
                           const float* __restrict__ stats, const float* __restrict__ g,
                           const float* __restrict__ bb, const int* __restrict__ row_ptr,
                           const uint2* __restrict__ edata,
                           const unsigned short* __restrict__ bsum_l,
                           const float* __restrict__ eps_ptr, unsigned short* __restrict__ Aout) {
    int n = blockIdx.x * 8 + (threadIdx.x >> 5);
    int lane = threadIdx.x & 31;
    int c0 = lane * 4;

    float bs[4] = {1.f, 1.f, 1.f, 1.f}, bt[4] = {0.f, 0.f, 0.f, 0.f};
    if (FUSE) {
        float4 gg = *(const float4*)(g + c0);
        float4 bv = *(const float4*)(bb + c0);
        float gv[4] = {gg.x, gg.y, gg.z, gg.w};
        float bbv[4] = {bv.x, bv.y, bv.z, bv.w};
#pragma unroll
        for (int k = 0; k < 4; k++) {
            float sm = stats[(size_t)(512 + c0 + k) * SPAD];
            float sq = stats[(size_t)(640 + c0 + k) * SPAD];
            float mean = sm * (1.f / NN);
            float var = sq * (1.f / NN) - mean * mean;
            bs[k] = gv[k] * rsqrtf(var + BN_EPS);
            bt[k] = bbv[k] - mean * bs[k];
        }
    }

    auto accum = [&](uint2 ed, uint2 hz, uint2 bz, float* acc) {
        float w = h2f((unsigned short)(ed.y >> 16));
        unsigned int hw[2] = {hz.x, hz.y}, bw[2] = {bz.x, bz.y};
#pragma unroll
        for (int k = 0; k < 2; k++) {
            float hv0 = h2f((unsigned short)(hw[k] & 0xffff));
            float hv1 = h2f((unsigned short)(hw[k] >> 16));
            if (FUSE) {
                hv0 = fmaxf(hv0 * bs[2 * k] + bt[2 * k], 0.f);
                hv1 = fmaxf(hv1 * bs[2 * k + 1] + bt[2 * k + 1], 0.f);
            }
            float m0 = fmaxf(hv0 + h2f((unsigned short)(bw[k] & 0xffff)), 0.f);
            float m1 = fmaxf(hv1 + h2f((unsigned short)(bw[k] >> 16)), 0.f);
            acc[2 * k] += m0 * w;
            acc[2 * k + 1] += m1 * w;
        }
    };

    int beg = row_ptr[n], end = row_ptr[n + 1];
    float acc[4] = {0.f, 0.f, 0.f, 0.f};
    int i = beg;
    for (; i + 4 <= end; i += 4) {
        uint2 e0 = edata[i], e1 = edata[i + 1], e2 = edata[i + 2], e3 = edata[i + 3];
        uint2 h0 = *(const uint2*)(hsrc + (size_t)e0.x * DD + c0);
        uint2 b0 = *(const uint2*)(bsum_l + (size_t)(e0.y & 0xffff) * DD + c0);
        uint2 h1 = *(const uint2*)(hsrc + (size_t)e1.x * DD + c0);
        uint2 b1 = *(const uint2*)(bsum_l + (size_t)(e1.y & 0xffff) * DD + c0);
        uint2 h2 = *(const uint2*)(hsrc + (size_t)e2.x * DD + c0);
        uint2 b2 = *(const uint2*)(bsum_l + (size_t)(e2.y & 0xffff) * DD + c0);
        uint2 h3 = *(const uint2*)(hsrc + (size_t)e3.x * DD + c0);
        uint2 b3 = *(const uint2*)(bsum_l + (size_t)(e3.y & 0xffff) * DD + c0);
        accum(e0, h0, b0, acc);
        accum(e1, h1, b1, acc);
        accum(e2, h2, b2, acc);
        accum(e3, h3, b3, acc);
    }
    for (; i < end; i++) {
        uint2 e0 = edata[i];
        uint2 h0 = *(const uint2*)(hsrc + (size_t)e0.x * DD + c0);
        uint2 b0 = *(const uint2*)(bsum_l + (size_t)(e0.y & 0xffff) * DD + c0);
        accum(e0, h0, b0, acc);
    }

    float eps1 = 1.f + eps_ptr[0];
    uint2 hz = *(const uint2*)(hsrc + (size_t)n * DD + c0);
    unsigned int hw[2] = {hz.x, hz.y};
    float self[4];
#pragma unroll
    for (int k = 0; k < 2; k++) {
        float hv0 = h2f((unsigned short)(hw[k] & 0xffff));
        float hv1 = h2f((unsigned short)(hw[k] >> 16));
        if (FUSE) {
            hv0 = fmaxf(hv0 * bs[2 * k] + bt[2 * k], 0.f);
            hv1 = fmaxf(hv1 * bs[2 * k + 1] + bt[2 * k + 1], 0.f);
        }
        self[2 * k] = hv0;
        self[2 * k + 1] = hv1;
    }
    ushort4 o;
    o.x = f2h_bits(eps1 * self[0] + acc[0]);
    o.y = f2h_bits(eps1 * self[1] + acc[1]);
    o.z = f2h_bits(eps1 * self[2] + acc[2]);
    o.w = f2h_bits(eps1 * self[3] + acc[3]);
    *(ushort4*)(Aout + (size_t)n * DD + c0) = o;
}

// ---------------- fused GEMM1 + BN1 + relu + GEMM2, z1 resident in LDS ----------------
// Persistent kernel, 512 blocks = exactly 2/CU (launch_bounds(256,2), 66KB LDS).
// Phase 1: z1 tile (64 rows x 256 cols) = A @ W1 + b1 -> LDS fp16 (+ padded col stats atomics).
// Fence-free hierarchical grid barrier. Phase 2: BN1 scale/shift broadcast via LDS, relu on
// LDS fragments, z2 = z1bn @ W2 + b2 -> global (+ padded stats2).
// MFMA operands swapped (A-op = weight frags, B-op = row frags) so the 4 acc elements per
// fragment are 4 CONSECUTIVE COLUMNS -> packed ushort4 LDS writes / global stores.
// LDS swizzle: phys = (row*512 + colbyte) ^ ((lr&7)<<4).
// statsL = this layer's padded region (see layout comment at top).

__global__ __launch_bounds__(256, 2) void fused_mlp_kernel(
    const unsigned short* __restrict__ A, const unsigned short* __restrict__ W1,
    const float* __restrict__ b1, const unsigned short* __restrict__ W2,
    const float* __restrict__ b2, const float* __restrict__ g1,
    const float* __restrict__ bb1, unsigned short* __restrict__ z2,
    float* __restrict__ statsL, int* bar) {
    __shared__ __align__(16) char ldsb[65536];  // 2 slots x [64 rows][256 cols] fp16
    __shared__ __align__(16) float st_sh[2 * DD2];  // BN1 scale/shift broadcast
    const int lane = threadIdx.x & 63;
    const int wave = threadIdx.x >> 6;
    const int lr = lane & 15;
    const int q = lane >> 4;
    const int swz = (lr & 7) << 4;

    // ---- phase 1 ----
    {
        const int wcol = wave * 64;  // this wave's 64-col slice of z1
        half8 wf[4][4];
#pragma unroll
        for (int jm = 0; jm < 4; jm++) {
            const unsigned short* p = W1 + (size_t)(wcol + jm * 16 + lr) * DD + q * 8;
#pragma unroll
            for (int ks = 0; ks < 4; ks++)
                wf[jm][ks] = __builtin_bit_cast(half8, *(const int4*)(p + ks * 32));
        }
        float bi[4][4];
#pragma unroll
        for (int jm = 0; jm < 4; jm++)
#pragma unroll
            for (int r = 0; r < 4; r++) bi[jm][r] = b1[wcol + jm * 16 + q * 4 + r];

        float s1[16], sq1[16];
#pragma unroll
        for (int k = 0; k < 16; k++) { s1[k] = 0.f; sq1[k] = 0.f; }

        for (int s = 0; s < 2; s++) {
            int t = blockIdx.x + s * GXF;
            if (t >= NT1) break;
            int row0 = t * 64;
            // OOB rows (>=NN, <50048) read benign ws poison; results never stored/counted
            const unsigned short* ap0 = A + (size_t)(row0 + lr) * DD + q * 8;
            f32x4 acc[4][4];
#pragma unroll
            for (int jm = 0; jm < 4; jm++)
#pragma unroll
                for (int in = 0; in < 4; in++) acc[jm][in] = (f32x4){0.f, 0.f, 0.f, 0.f};
#pragma unroll
            for (int ks = 0; ks < 4; ks++) {
                half8 rf[4];
#pragma unroll
                for (int in = 0; in < 4; in++)
                    rf[in] = __builtin_bit_cast(
                        half8, *(const int4*)(ap0 + (size_t)(in * 16) * DD + ks * 32));
#pragma unroll
                for (int jm = 0; jm < 4; jm++)
#pragma unroll
                    for (int in = 0; in < 4; in++)
                        acc[jm][in] = __builtin_amdgcn_mfma_f32_16x16x32_f16(
                            wf[jm][ks], rf[in], acc[jm][in], 0, 0, 0);
            }
            char* slot = ldsb + s * 32768;
#pragma unroll
            for (int in = 0; in < 4; in++) {
                int row = in * 16 + lr;
                bool rv = (row0 + row) < NN;
                int rbase = row * 512 + wave * 128;  // wave's 64-col (128 B) offset
#pragma unroll
                for (int jm = 0; jm < 4; jm++) {
                    ushort4 o;
#pragma unroll
                    for (int r = 0; r < 4; r++) {
                        float v = acc[jm][in][r] + bi[jm][r];
                        ((unsigned short*)&o)[r] = f2h_bits(v);
                        if (rv) {
                            s1[jm * 4 + r] += v;
                            sq1[jm * 4 + r] += v * v;
                        }
                    }
                    *(ushort4*)(slot + ((rbase + jm * 32 + q * 8) ^ swz)) = o;
                }
            }
        }
#pragma unroll
        for (int k = 0; k < 16; k++) {
            float a = s1[k], b = sq1[k];
#pragma unroll
            for (int m = 1; m < 16; m <<= 1) {
                a += __shfl_xor(a, m);
                b += __shfl_xor(b, m);
            }
            if (lr == 0) {
                int c = wcol + (k >> 2) * 16 + q * 4 + (k & 3);
                unsafeAtomicAdd(&statsL[(size_t)c * SPAD], a);
                unsafeAtomicAdd(&statsL[(size_t)(DD2 + c) * SPAD], b);
            }
        }
    }

    grid_barrier(bar);

    // ---- phase 2 ----
    {
        // BN1 scale/shift: one coalesced pass per block into LDS; sc1 relaxed loads
        for (int c = threadIdx.x; c < DD2; c += 256) {
            float sv = __hip_atomic_load(&statsL[(size_t)c * SPAD], __ATOMIC_RELAXED,
                                         __HIP_MEMORY_SCOPE_AGENT);
            float qv = __hip_atomic_load(&statsL[(size_t)(DD2 + c) * SPAD], __ATOMIC_RELAXED,
                                         __HIP_MEMORY_SCOPE_AGENT);
            float mean = sv * (1.f / NN);
            float var = qv * (1.f / NN) - mean * mean;
            float sc = g1[c] * rsqrtf(var + BN_EPS);
            st_sh[c] = sc;
            st_sh[DD2 + c] = bb1[c] - mean * sc;
        }
        __syncthreads();

        const int cb2 = wave * 32;  // this wave's 32-col slice of z2
        half8 sa[8], ta[8];
#pragma unroll
        for (int ks = 0; ks < 8; ks++) {
            const float* sp = st_sh + ks * 32 + q * 8;
            float4 sA = *(const float4*)(sp);
            float4 sB = *(const float4*)(sp + 4);
            float4 tA = *(const float4*)(sp + DD2);
            float4 tB = *(const float4*)(sp + DD2 + 4);
            sa[ks] = (half8){(_Float16)sA.x, (_Float16)sA.y, (_Float16)sA.z, (_Float16)sA.w,
                             (_Float16)sB.x, (_Float16)sB.y, (_Float16)sB.z, (_Float16)sB.w};
            ta[ks] = (half8){(_Float16)tA.x, (_Float16)tA.y, (_Float16)tA.z, (_Float16)tA.w,
                             (_Float16)tB.x, (_Float16)tB.y, (_Float16)tB.z, (_Float16)tB.w};
        }
        half8 wf2[2][8];
#pragma unroll
        for (int jm = 0; jm < 2; jm++) {
            const unsigned short* p = W2 + (size_t)(cb2 + jm * 16 + lr) * DD2 + q * 8;
#pragma unroll
            for (int ks = 0; ks < 8; ks++)
                wf2[jm][ks] = __builtin_bit_cast(half8, *(const int4*)(p + ks * 32));
        }
        float bi2[2][4];
#pragma unroll
        for (int jm = 0; jm < 2; jm++)
#pragma unroll
            for (int r = 0; r < 4; r++) bi2[jm][r] = b2[cb2 + jm * 16 + q * 4 + r];

        float s2[8], sq2[8];
#pragma unroll
        for (int k = 0; k < 8; k++) { s2[k] = 0.f; sq2[k] = 0.f; }

        for (int s = 0; s < 2; s++) {
            int t = blockIdx.x + s * GXF;
            if (t >= NT1) break;
            int row0 = t * 64;
            char* slot = ldsb + s * 32768;
            f32x4 acc[2][4];
#pragma unroll
            for (int jm = 0; jm < 2; jm++)
#pragma unroll
                for (int in = 0; in < 4; in++) acc[jm][in] = (f32x4){0.f, 0.f, 0.f, 0.f};
#pragma unroll
            for (int ks = 0; ks < 8; ks++) {
                half8 rf[4];
#pragma unroll
                for (int in = 0; in < 4; in++) {
                    int row = in * 16 + lr;
                    half8 z = *(const half8*)(slot + ((row * 512 + ks * 64 + q * 16) ^ swz));
                    rf[in] = bnrelu8(z, sa[ks], ta[ks]);
                }
#pragma unroll
                for (int jm = 0; jm < 2; jm++)
#pragma unroll
                    for (int in = 0; in < 4; in++)
                        acc[jm][in] = __builtin_amdgcn_mfma_f32_16x16x32_f16(
                            wf2[jm][ks], rf[in], acc[jm][in], 0, 0, 0);
            }
#pragma unroll
            for (int in = 0; in < 4; in++) {
                int row = row0 + in * 16 + lr;
                if (row < NN) {
#pragma unroll
                    for (int jm = 0; jm < 2; jm++) {
                        ushort4 o;
#pragma unroll
                        for (int r = 0; r < 4; r++) {
                            float v = acc[jm][in][r] + bi2[jm][r];
                            ((unsigned short*)&o)[r] = f2h_bits(v);
                            s2[jm * 4 + r] += v;
                            sq2[jm * 4 + r] += v * v;
                        }
                        *(ushort4*)(z2 + (size_t)row * DD + cb2 + jm * 16 + q * 4) = o;
                    }
                }
            }
        }
#pragma unroll
        for (int k = 0; k < 8; k++) {
            float a = s2[k], b = sq2[k];
#pragma unroll
            for (int m = 1; m < 16; m <<= 1) {
                a += __shfl_xor(a, m);
                b += __shfl_xor(b, m);
            }
            if (lr == 0) {
                int c = cb2 + (k >> 2) * 16 + q * 4 + (k & 3);
                unsafeAtomicAdd(&statsL[(size_t)(512 + c) * SPAD], a);
                unsafeAtomicAdd(&statsL[(size_t)(640 + c) * SPAD], b);
            }
        }
    }
}

// ---------------- BN apply 2, last layer only: z2 fp16 -> d_out fp32 (no relu) ---------------
// stats = padded last-layer region.

__global__ void bnapply2_last_kernel(const unsigned short* __restrict__ z,
                                     const float* __restrict__ stats, const float* __restrict__ g,
                                     const float* __restrict__ bb, float* __restrict__ fout) {
    __shared__ float s_sh[DD], t_sh[DD];
    if (threadIdx.x < DD) {
        int c = threadIdx.x;
        float mean = stats[(size_t)(512 + c) * SPAD] * (1.f / NN);
        float var = stats[(size_t)(640 + c) * SPAD] * (1.f / NN) - mean * mean;
        float sc = g[c] * rsqrtf(var + BN_EPS);
        s_sh[c] = sc;
        t_sh[c] = bb[c] - mean * sc;
    }
    __syncthreads();
    int i = (blockIdx.x * 256 + threadIdx.x) * 4;
    int c = i & 127;
    uint2 in = *(const uint2*)(z + i);
    float4 out;
    out.x = h2f((unsigned short)(in.x & 0xffff)) * s_sh[c] + t_sh[c];
    out.y = h2f((unsigned short)(in.x >> 16)) * s_sh[c + 1] + t_sh[c + 1];
    out.z = h2f((unsigned short)(in.y & 0xffff)) * s_sh[c + 2] + t_sh[c + 2];
    out.w = h2f((unsigned short)(in.y >> 16)) * s_sh[c + 3] + t_sh[c + 3];
    *(float4*)(fout + i) = out;
}

// ---------------- launch ----------------

extern "C" void kernel_launch(void* const* d_in, const int* in_sizes, int n_in,
                              void* d_out, int out_size, void* d_ws, size_t ws_size,
                              hipStream_t stream) {
    const int* x = (const int*)d_in[0];
    const int* edge_index = (const int*)d_in[1];
    const int* edge_attr = (const int*)d_in[2];
    const float* edge_weight = (const float*)d_in[3];
    const float* atom_emb = (const float*)d_in[4];
    const float* bond_emb = (const float*)d_in[5];
    const float* W1 = (const float*)d_in[6];
    const float* b1 = (const float*)d_in[7];
    const float* bn1_g = (const float*)d_in[8];
    const float* bn1_b = (const float*)d_in[9];
    const float* W2 = (const float*)d_in[10];
    const float* b2 = (const float*)d_in[11];
    const float* eps_p = (const float*)d_in[12];
    const float* bn_g = (const float*)d_in[13];
    const float* bn_b = (const float*)d_in[14];
    const int* srcv = edge_index;
    const int* dstv = edge_index + EE;

    char* p = (char*)d_ws;
    auto alloc = [&](size_t bytes) {
        void* r = (void*)p;
        p += (bytes + 255) & ~(size_t)255;
        return r;
    };
    // A1h padded to NT1*64 rows so fused kernel's tail-tile reads stay in-buffer
    unsigned short* h = (unsigned short*)alloc((size_t)NN * DD * 2);
    unsigned short* A1h = (unsigned short*)alloc((size_t)(NT1 * 64) * DD * 2);
    unsigned short* z2 = (unsigned short*)alloc((size_t)NN * DD * 2);
    uint2* edata = (uint2*)alloc((size_t)EE * 8);
    int* counts = (int*)alloc((size_t)NN * 4);
    int* row_ptr = (int*)alloc((size_t)(NN + 1) * 4);
    int* blksum = (int*)alloc(256 * 4);
    unsigned short* W1t = (unsigned short*)alloc((size_t)LL * DD * DD2 * 2);
    unsigned short* W2t = (unsigned short*)alloc((size_t)LL * DD * DD2 * 2);
    unsigned short* bsum = (unsigned short*)alloc((size_t)LL * 512 * DD * 2);
    // padded stats (768 slots x SPAD floats per layer) + barrier slots (160 ints per layer),
    // zeroed together in-graph so every replay resets them
    const size_t statsFloats = (size_t)LL * 768 * SPAD;
    const size_t barInts = (size_t)LL * 160;
    float* statsP = (float*)alloc(statsFloats * 4 + barInts * 4);
    int* barBase = (int*)(statsP + statsFloats);

    // --- one-time prep ---
    hipMemsetAsync(counts, 0, (size_t)NN * 4, stream);
    hipMemsetAsync(statsP, 0, statsFloats * 4 + barInts * 4, stream);
    hist_kernel<<<(EE + 255) / 256, 256, 0, stream>>>(dstv, counts);
    int nblk = (NN + 255) / 256;
    scan1_kernel<<<nblk, 256, 0, stream>>>(counts, row_ptr, blksum);
    scan2_kernel<<<1, 256, 0, stream>>>(blksum, nblk);
    scan3_kernel<<<nblk, 256, 0, stream>>>(row_ptr, blksum);
    hipMemsetAsync(counts, 0, (size_t)NN * 4, stream);
    scatter_kernel<<<(EE + 255) / 256, 256, 0, stream>>>(dstv, srcv, edge_attr, edge_weight,
                                                         row_ptr, counts, edata);
    prep_tables_kernel<<<(2 * LL * DD * DD2 + LL * 512 * DD + 255) / 256, 256, 0, stream>>>(
        W1, W2, bond_emb, W1t, W2t, bsum);
    init_h_kernel<<<NN / 8, 256, 0, stream>>>(x, atom_emb, h);

    for (int l = 0; l < LL; l++) {
        float* statsL = statsP + (size_t)l * 768 * SPAD;
        const unsigned short* bsum_l = bsum + (size_t)l * 512 * DD;

        if (l == 0) {
            agg_kernel<false><<<NN / 8, 256, 0, stream>>>(h, nullptr, nullptr, nullptr, row_ptr,
                                                          edata, bsum_l, eps_p + l, A1h);
        } else {
            agg_kernel<true><<<NN / 8, 256, 0, stream>>>(
                z2, statsP + (size_t)(l - 1) * 768 * SPAD, bn_g + (l - 1) * DD,
                bn_b + (l - 1) * DD, row_ptr, edata, bsum_l, eps_p + l, A1h);
        }

        fused_mlp_kernel<<<GXF, 256, 0, stream>>>(
            A1h, W1t + (size_t)l * DD * DD2, b1 + l * DD2, W2t + (size_t)l * DD * DD2,
            b2 + l * DD, bn1_g + l * DD2, bn1_b + l * DD2, z2, statsL, barBase + l * 160);
    }

    bnapply2_last_kernel<<<NN * DD / 1024, 256, 0, stream>>>(
        z2, statsP + (size_t)(LL - 1) * 768 * SPAD, bn_g + (LL - 1) * DD, bn_b + (LL - 1) * DD,
        (float*)d_out);
}